// Round 3
// baseline (695.348 us; speedup 1.0000x reference)
//
#include <hip/hip_runtime.h>
#include <math.h>

#define T_TOK 4096
#define H_DIM 1024
#define E_NUM 8
#define I_DIM 4096

typedef __attribute__((ext_vector_type(4))) float f32x4;
typedef __attribute__((ext_vector_type(8))) short bf16x8;

__device__ inline unsigned short f2bf(float f) {
  unsigned int u = __float_as_uint(f);
  u += 0x7fffu + ((u >> 16) & 1u);   // RNE (finite data only)
  return (unsigned short)(u >> 16);
}

__device__ inline void cvt_store4(unsigned short* dst, const float* src) {
  f32x4 v = *reinterpret_cast<const f32x4*>(src);
  ushort4 o;
  o.x = f2bf(v[0]); o.y = f2bf(v[1]); o.z = f2bf(v[2]); o.w = f2bf(v[3]);
  *reinterpret_cast<ushort4*>(dst) = o;
}

// async global->LDS, 16B per lane; LDS dest is wave-uniform base + lane*16
__device__ inline void gll16(const void* g, void* l) {
  __builtin_amdgcn_global_load_lds(
      (const __attribute__((address_space(1))) void*)g,
      (__attribute__((address_space(3))) void*)l, 16, 0, 0);
}

// ---------------- router: fp32 logits, exact top-2 + softmax ----------------
__global__ __launch_bounds__(64) void k_router(const float* __restrict__ x,
                                               const float* __restrict__ gw,
                                               int2* __restrict__ tokE,
                                               float2* __restrict__ tokP,
                                               int* __restrict__ counts) {
  const int t = blockIdx.x;
  const int l = threadIdx.x;
  const float* xr = x + (size_t)t * H_DIM;
  float acc[E_NUM];
#pragma unroll
  for (int e = 0; e < E_NUM; e++) acc[e] = 0.f;
  for (int h = l; h < H_DIM; h += 64) {
    float xv = xr[h];
#pragma unroll
    for (int e = 0; e < E_NUM; e++) acc[e] += xv * gw[e * H_DIM + h];
  }
#pragma unroll
  for (int e = 0; e < E_NUM; e++) {
#pragma unroll
    for (int off = 32; off > 0; off >>= 1) acc[e] += __shfl_xor(acc[e], off);
  }
  if (l == 0) {
    float v0 = -1e30f, v1 = -1e30f;
    int e0 = 0, e1 = 0;
#pragma unroll
    for (int e = 0; e < E_NUM; e++) {
      float v = acc[e];
      if (v > v0) { v1 = v0; e1 = e0; v0 = v; e0 = e; }
      else if (v > v1) { v1 = v; e1 = e; }
    }
    float ex = expf(v1 - v0);
    float p0 = 1.f / (1.f + ex);
    float p1 = ex * p0;
    tokE[t] = make_int2(e0, e1);
    tokP[t] = make_float2(p0, p1);
    atomicAdd(&counts[e0], 1);
    atomicAdd(&counts[e1], 1);
  }
}

__global__ void k_offsets(const int* __restrict__ counts, int* __restrict__ offsets) {
  if (threadIdx.x == 0 && blockIdx.x == 0) {
    int s = 0;
    for (int e = 0; e < E_NUM; e++) { offsets[e] = s; s += counts[e]; }
    offsets[E_NUM] = s;
  }
}

__global__ __launch_bounds__(256) void k_scatter(const int2* __restrict__ tokE,
                                                 const float2* __restrict__ tokP,
                                                 const int* __restrict__ offsets,
                                                 int* __restrict__ cursor,
                                                 int* __restrict__ slot_tok,
                                                 float* __restrict__ slot_w) {
  int t = blockIdx.x * 256 + threadIdx.x;
  if (t >= T_TOK) return;
  int2 e = tokE[t];
  float2 p = tokP[t];
  int pos0 = atomicAdd(&cursor[e.x], 1);
  slot_tok[offsets[e.x] + pos0] = t;
  slot_w[offsets[e.x] + pos0] = p.x;
  int pos1 = atomicAdd(&cursor[e.y], 1);
  slot_tok[offsets[e.y] + pos1] = t;
  slot_w[offsets[e.y] + pos1] = p.y;
}

// ---------------- fp32 -> bf16 bulk convert (memory-bound) ------------------
__global__ __launch_bounds__(256) void k_cvt(const float* __restrict__ src,
                                             unsigned short* __restrict__ dst,
                                             int n4) {
  int i = blockIdx.x * 256 + threadIdx.x;
  const int stride = gridDim.x * 256;
  for (; i < n4; i += stride) {
    f32x4 v = reinterpret_cast<const f32x4*>(src)[i];
    ushort4 o;
    o.x = f2bf(v[0]); o.y = f2bf(v[1]); o.z = f2bf(v[2]); o.w = f2bf(v[3]);
    reinterpret_cast<ushort4*>(dst)[i] = o;
  }
}

// ============ 8-phase deep-pipelined grouped GEMMs (T2+T3+T4+T5) ============
// Common geometry: BM=256 (tokens), BN=128, BK=64, 512 threads = 8 waves
// (2M x 4N), wave tile 128x32. LDS XOR-swizzle: 16B chunk c of row r lives at
// chunk (c ^ (r&7)) -- applied on the global SOURCE address for staging and on
// the ds_read side (rule #21). Raw s_barrier + counted vmcnt (never 0 in the
// main loop). One logical "issue" = 64 rows x 64 cols bf16 = 8 KiB = 1 gll16
// per wave (wave w stages rows w*8..w*8+7 of the issue).

// pass 1: hidden = silu(Xe @ wg^T) * (Xe @ wu^T)   [dual-B]
__global__ __launch_bounds__(512, 2) void k_gateup8(
    const unsigned short* __restrict__ xb, const unsigned short* __restrict__ wgb,
    const unsigned short* __restrict__ wub, const int* __restrict__ counts,
    const int* __restrict__ offsets, const int* __restrict__ slot_tok,
    unsigned short* __restrict__ hidden) {
  const int e = blockIdx.z;
  const int cnt = counts[e];
  const int m0 = blockIdx.y * 256;
  if (m0 >= cnt) return;
  const int n0 = blockIdx.x * 128;
  const int base = offsets[e];

  __shared__ unsigned short As[2][256 * 64];   // 64 KiB
  __shared__ unsigned short Bgs[2][128 * 64];  // 32 KiB
  __shared__ unsigned short Bus[2][128 * 64];  // 32 KiB

  const int tid = threadIdx.x;
  const int wave = tid >> 6;
  const int lane = tid & 63;
  const int wm = (wave >> 2) * 128;   // wave_m * 128
  const int wn = (wave & 3) * 32;     // wave_n * 32
  const int lr = lane & 15;
  const int lk = lane >> 4;
  const int xr = lr & 7;

  const int srow = lane >> 3;         // 0..7
  const int schk = lane & 7;          // 0..7
  const int swz = ((schk ^ srow) << 3);
  const int ldsw = wave * 8 * 64;     // wave's slice within a 64-row issue

  const size_t wboff = (size_t)e * (size_t)I_DIM * H_DIM;
  const unsigned short* pA[4];
  const unsigned short* pBg[2];
  const unsigned short* pBu[2];
#pragma unroll
  for (int i = 0; i < 4; i++) {
    int r = i * 64 + wave * 8 + srow;
    int gr = m0 + r; if (gr > cnt - 1) gr = cnt - 1;
    pA[i] = xb + (size_t)slot_tok[base + gr] * H_DIM + swz;
  }
#pragma unroll
  for (int i = 0; i < 2; i++) {
    int r = i * 64 + wave * 8 + srow;
    pBg[i] = wgb + wboff + (size_t)(n0 + r) * H_DIM + swz;
    pBu[i] = wub + wboff + (size_t)(n0 + r) * H_DIM + swz;
  }

  f32x4 accg[8][2], accu[8][2];
#pragma unroll
  for (int i = 0; i < 8; i++)
#pragma unroll
    for (int j = 0; j < 2; j++) {
      accg[i][j] = (f32x4){0.f, 0.f, 0.f, 0.f};
      accu[i][j] = (f32x4){0.f, 0.f, 0.f, 0.f};
    }

  const int ar = (wm + lr) * 64;
  const int br = (wn + lr) * 64;
  const int c0 = ((lk ^ xr) << 3);          // kh=0 column chunk (swizzled)
  const int c1 = (((4 + lk) ^ xr) << 3);    // kh=1

  bf16x8 fg[2][2], fu[2][2];

  // prologue: canonical issue order (matches steady-state order)
  gll16(pBg[0], &Bgs[0][0 * 4096 + ldsw]);
  gll16(pBg[1], &Bgs[0][1 * 4096 + ldsw]);
  gll16(pBu[0], &Bus[0][0 * 4096 + ldsw]);
  gll16(pBu[1], &Bus[0][1 * 4096 + ldsw]);
  gll16(pA[0], &As[0][0 * 4096 + ldsw]);
  gll16(pA[2], &As[0][2 * 4096 + ldsw]);
  gll16(pA[1], &As[0][1 * 4096 + ldsw]);
  gll16(pA[3], &As[0][3 * 4096 + ldsw]);

#define GU_PHASE(P, CUR, NXT, KNXT)                                            \
  do {                                                                         \
    if ((P) == 0) {                                                            \
      gll16(pBg[0] + (KNXT), &Bgs[NXT][0 * 4096 + ldsw]);                      \
      gll16(pBg[1] + (KNXT), &Bgs[NXT][1 * 4096 + ldsw]);                      \
      asm volatile("s_waitcnt vmcnt(4)" ::: "memory");                         \
    } else if ((P) == 1) {                                                     \
      gll16(pBu[0] + (KNXT), &Bus[NXT][0 * 4096 + ldsw]);                      \
      gll16(pBu[1] + (KNXT), &Bus[NXT][1 * 4096 + ldsw]);                      \
    } else if ((P) == 2) {                                                     \
      gll16(pA[0] + (KNXT), &As[NXT][0 * 4096 + ldsw]);                        \
      gll16(pA[2] + (KNXT), &As[NXT][2 * 4096 + ldsw]);                        \
      asm volatile("s_waitcnt vmcnt(6)" ::: "memory");                         \
    } else {                                                                   \
      gll16(pA[1] + (KNXT), &As[NXT][1 * 4096 + ldsw]);                        \
      gll16(pA[3] + (KNXT), &As[NXT][3 * 4096 + ldsw]);                        \
    }                                                                          \
    __builtin_amdgcn_s_barrier();                                              \
    if ((P) == 0) {                                                            \
      _Pragma("unroll") for (int nf = 0; nf < 2; nf++) {                       \
        fg[nf][0] = *(const bf16x8*)&Bgs[CUR][br + nf * 1024 + c0];            \
        fg[nf][1] = *(const bf16x8*)&Bgs[CUR][br + nf * 1024 + c1];            \
        fu[nf][0] = *(const bf16x8*)&Bus[CUR][br + nf * 1024 + c0];            \
        fu[nf][1] = *(const bf16x8*)&Bus[CUR][br + nf * 1024 + c1];            \
      }                                                                        \
    }                                                                          \
    bf16x8 a00 = *(const bf16x8*)&As[CUR][ar + (2 * (P)) * 1024 + c0];         \
    bf16x8 a01 = *(const bf16x8*)&As[CUR][ar + (2 * (P)) * 1024 + c1];         \
    bf16x8 a10 = *(const bf16x8*)&As[CUR][ar + (2 * (P) + 1) * 1024 + c0];     \
    bf16x8 a11 = *(const bf16x8*)&As[CUR][ar + (2 * (P) + 1) * 1024 + c1];     \
    __builtin_amdgcn_s_setprio(1);                                             \
    _Pragma("unroll") for (int nf = 0; nf < 2; nf++) {                         \
      accg[2*(P)][nf]   = __builtin_amdgcn_mfma_f32_16x16x32_bf16(a00, fg[nf][0], accg[2*(P)][nf], 0, 0, 0);     \
      accg[2*(P)][nf]   = __builtin_amdgcn_mfma_f32_16x16x32_bf16(a01, fg[nf][1], accg[2*(P)][nf], 0, 0, 0);     \
      accu[2*(P)][nf]   = __builtin_amdgcn_mfma_f32_16x16x32_bf16(a00, fu[nf][0], accu[2*(P)][nf], 0, 0, 0);     \
      accu[2*(P)][nf]   = __builtin_amdgcn_mfma_f32_16x16x32_bf16(a01, fu[nf][1], accu[2*(P)][nf], 0, 0, 0);     \
      accg[2*(P)+1][nf] = __builtin_amdgcn_mfma_f32_16x16x32_bf16(a10, fg[nf][0], accg[2*(P)+1][nf], 0, 0, 0);   \
      accg[2*(P)+1][nf] = __builtin_amdgcn_mfma_f32_16x16x32_bf16(a11, fg[nf][1], accg[2*(P)+1][nf], 0, 0, 0);   \
      accu[2*(P)+1][nf] = __builtin_amdgcn_mfma_f32_16x16x32_bf16(a10, fu[nf][0], accu[2*(P)+1][nf], 0, 0, 0);   \
      accu[2*(P)+1][nf] = __builtin_amdgcn_mfma_f32_16x16x32_bf16(a11, fu[nf][1], accu[2*(P)+1][nf], 0, 0, 0);   \
    }                                                                          \
    __builtin_amdgcn_s_setprio(0);                                             \
    __builtin_amdgcn_s_barrier();                                              \
  } while (0)

#define GU_STEP(CUR, NXT, KNXT) \
  GU_PHASE(0, CUR, NXT, KNXT);  \
  GU_PHASE(1, CUR, NXT, KNXT);  \
  GU_PHASE(2, CUR, NXT, KNXT);  \
  GU_PHASE(3, CUR, NXT, KNXT);

  for (int t = 0; t < 16; t += 2) {
    const int k1 = (t + 1) * 64;
    const int k2 = (t + 2 < 16) ? (t + 2) * 64 : 0;  // wrap: dummy in-bounds prefetch
    GU_STEP(0, 1, k1);
    GU_STEP(1, 0, k2);
  }
#undef GU_PHASE
#undef GU_STEP

#pragma unroll
  for (int mf = 0; mf < 8; mf++) {
#pragma unroll
    for (int j = 0; j < 4; j++) {
      int row = wm + mf * 16 + lk * 4 + j;
      if (m0 + row < cnt) {
        size_t hbase = (size_t)(base + m0 + row) * I_DIM;
#pragma unroll
        for (int nf = 0; nf < 2; nf++) {
          int col = n0 + wn + nf * 16 + lr;
          float g = accg[mf][nf][j];
          float u = accu[mf][nf][j];
          hidden[hbase + col] = f2bf(g / (1.f + expf(-g)) * u);
        }
      }
    }
  }
}

// pass 2: out[t] += w * (hidden_row @ wd^T)   [single-B, K=I=4096]
__global__ __launch_bounds__(512, 2) void k_down8(
    const unsigned short* __restrict__ hidden, const unsigned short* __restrict__ wdb,
    const int* __restrict__ counts, const int* __restrict__ offsets,
    const int* __restrict__ slot_tok, const float* __restrict__ slot_w,
    float* __restrict__ out) {
  const int e = blockIdx.z;
  const int cnt = counts[e];
  const int m0 = blockIdx.y * 256;
  if (m0 >= cnt) return;
  const int n0 = blockIdx.x * 128;
  const int base = offsets[e];

  __shared__ unsigned short As[2][256 * 64];   // 64 KiB
  __shared__ unsigned short Bs[2][128 * 64];   // 32 KiB

  const int tid = threadIdx.x;
  const int wave = tid >> 6;
  const int lane = tid & 63;
  const int wm = (wave >> 2) * 128;
  const int wn = (wave & 3) * 32;
  const int lr = lane & 15;
  const int lk = lane >> 4;
  const int xr = lr & 7;

  const int srow = lane >> 3;
  const int schk = lane & 7;
  const int swz = ((schk ^ srow) << 3);
  const int ldsw = wave * 8 * 64;

  const unsigned short* pA[4];
  const unsigned short* pB[2];
#pragma unroll
  for (int i = 0; i < 4; i++) {
    int r = i * 64 + wave * 8 + srow;
    int gr = m0 + r; if (gr > cnt - 1) gr = cnt - 1;
    pA[i] = hidden + (size_t)(base + gr) * I_DIM + swz;
  }
#pragma unroll
  for (int i = 0; i < 2; i++) {
    int r = i * 64 + wave * 8 + srow;
    pB[i] = wdb + (size_t)e * H_DIM * I_DIM + (size_t)(n0 + r) * I_DIM + swz;
  }

  f32x4 acc[8][2];
#pragma unroll
  for (int i = 0; i < 8; i++)
#pragma unroll
    for (int j = 0; j < 2; j++) acc[i][j] = (f32x4){0.f, 0.f, 0.f, 0.f};

  const int ar = (wm + lr) * 64;
  const int br = (wn + lr) * 64;
  const int c0 = ((lk ^ xr) << 3);
  const int c1 = (((4 + lk) ^ xr) << 3);

  bf16x8 fb[2][2];

  // prologue (canonical order: B0,B1,A0 | A2,A1,A3)
  gll16(pB[0], &Bs[0][0 * 4096 + ldsw]);
  gll16(pB[1], &Bs[0][1 * 4096 + ldsw]);
  gll16(pA[0], &As[0][0 * 4096 + ldsw]);
  gll16(pA[2], &As[0][2 * 4096 + ldsw]);
  gll16(pA[1], &As[0][1 * 4096 + ldsw]);
  gll16(pA[3], &As[0][3 * 4096 + ldsw]);

#define DN_PHASE(P, CUR, NXT, KNXT)                                            \
  do {                                                                         \
    if ((P) == 0) {                                                            \
      gll16(pB[0] + (KNXT), &Bs[NXT][0 * 4096 + ldsw]);                        \
      gll16(pB[1] + (KNXT), &Bs[NXT][1 * 4096 + ldsw]);                        \
      gll16(pA[0] + (KNXT), &As[NXT][0 * 4096 + ldsw]);                        \
      asm volatile("s_waitcnt vmcnt(5)" ::: "memory");                         \
    } else {                                                                   \
      gll16(pA[2] + (KNXT), &As[NXT][2 * 4096 + ldsw]);                        \
      gll16(pA[1] + (KNXT), &As[NXT][1 * 4096 + ldsw]);                        \
      gll16(pA[3] + (KNXT), &As[NXT][3 * 4096 + ldsw]);                        \
      asm volatile("s_waitcnt vmcnt(6)" ::: "memory");                         \
    }                                                                          \
    __builtin_amdgcn_s_barrier();                                              \
    if ((P) == 0) {                                                            \
      _Pragma("unroll") for (int nf = 0; nf < 2; nf++) {                       \
        fb[nf][0] = *(const bf16x8*)&Bs[CUR][br + nf * 1024 + c0];             \
        fb[nf][1] = *(const bf16x8*)&Bs[CUR][br + nf * 1024 + c1];             \
      }                                                                        \
    }                                                                          \
    bf16x8 a0k0 = *(const bf16x8*)&As[CUR][ar + (4 * (P) + 0) * 1024 + c0];    \
    bf16x8 a0k1 = *(const bf16x8*)&As[CUR][ar + (4 * (P) + 0) * 1024 + c1];    \
    bf16x8 a1k0 = *(const bf16x8*)&As[CUR][ar + (4 * (P) + 1) * 1024 + c0];    \
    bf16x8 a1k1 = *(const bf16x8*)&As[CUR][ar + (4 * (P) + 1) * 1024 + c1];    \
    bf16x8 a2k0 = *(const bf16x8*)&As[CUR][ar + (4 * (P) + 2) * 1024 + c0];    \
    bf16x8 a2k1 = *(const bf16x8*)&As[CUR][ar + (4 * (P) + 2) * 1024 + c1];    \
    bf16x8 a3k0 = *(const bf16x8*)&As[CUR][ar + (4 * (P) + 3) * 1024 + c0];    \
    bf16x8 a3k1 = *(const bf16x8*)&As[CUR][ar + (4 * (P) + 3) * 1024 + c1];    \
    __builtin_amdgcn_s_setprio(1);                                             \
    _Pragma("unroll") for (int nf = 0; nf < 2; nf++) {                         \
      acc[4*(P)+0][nf] = __builtin_amdgcn_mfma_f32_16x16x32_bf16(a0k0, fb[nf][0], acc[4*(P)+0][nf], 0, 0, 0);  \
      acc[4*(P)+0][nf] = __builtin_amdgcn_mfma_f32_16x16x32_bf16(a0k1, fb[nf][1], acc[4*(P)+0][nf], 0, 0, 0);  \
      acc[4*(P)+1][nf] = __builtin_amdgcn_mfma_f32_16x16x32_bf16(a1k0, fb[nf][0], acc[4*(P)+1][nf], 0, 0, 0);  \
      acc[4*(P)+1][nf] = __builtin_amdgcn_mfma_f32_16x16x32_bf16(a1k1, fb[nf][1], acc[4*(P)+1][nf], 0, 0, 0);  \
      acc[4*(P)+2][nf] = __builtin_amdgcn_mfma_f32_16x16x32_bf16(a2k0, fb[nf][0], acc[4*(P)+2][nf], 0, 0, 0);  \
      acc[4*(P)+2][nf] = __builtin_amdgcn_mfma_f32_16x16x32_bf16(a2k1, fb[nf][1], acc[4*(P)+2][nf], 0, 0, 0);  \
      acc[4*(P)+3][nf] = __builtin_amdgcn_mfma_f32_16x16x32_bf16(a3k0, fb[nf][0], acc[4*(P)+3][nf], 0, 0, 0);  \
      acc[4*(P)+3][nf] = __builtin_amdgcn_mfma_f32_16x16x32_bf16(a3k1, fb[nf][1], acc[4*(P)+3][nf], 0, 0, 0);  \
    }                                                                          \
    __builtin_amdgcn_s_setprio(0);                                             \
    __builtin_amdgcn_s_barrier();                                              \
  } while (0)

#define DN_STEP(CUR, NXT, KNXT) \
  DN_PHASE(0, CUR, NXT, KNXT);  \
  DN_PHASE(1, CUR, NXT, KNXT);

  for (int t = 0; t < 64; t += 2) {
    const int k1 = (t + 1) * 64;
    const int k2 = (t + 2 < 64) ? (t + 2) * 64 : 0;
    DN_STEP(0, 1, k1);
    DN_STEP(1, 0, k2);
  }
#undef DN_PHASE
#undef DN_STEP

#pragma unroll
  for (int mf = 0; mf < 8; mf++) {
#pragma unroll
    for (int j = 0; j < 4; j++) {
      int row = wm + mf * 16 + lk * 4 + j;
      if (m0 + row < cnt) {
        int slot = base + m0 + row;
        int t = slot_tok[slot];
        float w = slot_w[slot];
#pragma unroll
        for (int nf = 0; nf < 2; nf++) {
          int col = n0 + wn + nf * 16 + lr;
          atomicAdd(&out[(size_t)t * H_DIM + col], w * acc[mf][nf][j]);
        }
      }
    }
  }
}

// ================= FALLBACK PATH (fp32 in-loop convert, proven) =============
__global__ __launch_bounds__(256) void k_gateup_v1(
    const float* __restrict__ x, const float* __restrict__ wg,
    const float* __restrict__ wu, const int* __restrict__ counts,
    const int* __restrict__ offsets, const int* __restrict__ slot_tok,
    unsigned short* __restrict__ hidden) {
  const int e = blockIdx.z;
  const int cnt = counts[e];
  const int m0 = blockIdx.y * 128;
  if (m0 >= cnt) return;
  const int n0 = blockIdx.x * 128;
  const int base = offsets[e];

  __shared__ unsigned short As[128 * 40];
  __shared__ unsigned short Bgs[128 * 40];
  __shared__ unsigned short Bus[128 * 40];

  const int tid = threadIdx.x;
  const int wave = tid >> 6;
  const int lane = tid & 63;
  const int wm = (wave >> 1) * 64;
  const int wn = (wave & 1) * 64;
  const int lr = lane & 15;
  const int lk = lane >> 4;
  const int r_sub = tid >> 3;
  const int kq = (tid & 7) * 4;

  const float* wge = wg + (size_t)e * I_DIM * H_DIM;
  const float* wue = wu + (size_t)e * I_DIM * H_DIM;

  const float* aptr[4];
  const float* bgptr[4];
  const float* buptr[4];
#pragma unroll
  for (int p = 0; p < 4; p++) {
    int row = p * 32 + r_sub;
    int gr = m0 + row;
    if (gr > cnt - 1) gr = cnt - 1;
    aptr[p] = x + (size_t)slot_tok[base + gr] * H_DIM + kq;
    bgptr[p] = wge + (size_t)(n0 + row) * H_DIM + kq;
    buptr[p] = wue + (size_t)(n0 + row) * H_DIM + kq;
  }

  f32x4 accg[4][4], accu[4][4];
#pragma unroll
  for (int i = 0; i < 4; i++)
#pragma unroll
    for (int j = 0; j < 4; j++) {
      accg[i][j] = (f32x4){0.f, 0.f, 0.f, 0.f};
      accu[i][j] = (f32x4){0.f, 0.f, 0.f, 0.f};
    }

  for (int k0 = 0; k0 < H_DIM; k0 += 32) {
#pragma unroll
    for (int p = 0; p < 4; p++) {
      int row = p * 32 + r_sub;
      cvt_store4(&As[row * 40 + kq], aptr[p] + k0);
      cvt_store4(&Bgs[row * 40 + kq], bgptr[p] + k0);
      cvt_store4(&Bus[row * 40 + kq], buptr[p] + k0);
    }
    __syncthreads();
    bf16x8 af[4];
#pragma unroll
    for (int mf = 0; mf < 4; mf++)
      af[mf] = *reinterpret_cast<const bf16x8*>(&As[(wm + mf * 16 + lr) * 40 + lk * 8]);
#pragma unroll
    for (int nf = 0; nf < 4; nf++) {
      bf16x8 bg = *reinterpret_cast<const bf16x8*>(&Bgs[(wn + nf * 16 + lr) * 40 + lk * 8]);
      bf16x8 bu = *reinterpret_cast<const bf16x8*>(&Bus[(wn + nf * 16 + lr) * 40 + lk * 8]);
#pragma unroll
      for (int mf = 0; mf < 4; mf++) {
        accg[mf][nf] = __builtin_amdgcn_mfma_f32_16x16x32_bf16(af[mf], bg, accg[mf][nf], 0, 0, 0);
        accu[mf][nf] = __builtin_amdgcn_mfma_f32_16x16x32_bf16(af[mf], bu, accu[mf][nf], 0, 0, 0);
      }
    }
    __syncthreads();
  }

#pragma unroll
  for (int mf = 0; mf < 4; mf++) {
#pragma unroll
    for (int j = 0; j < 4; j++) {
      int row = wm + mf * 16 + lk * 4 + j;
      if (m0 + row < cnt) {
        size_t hbase = (size_t)(base + m0 + row) * I_DIM;
#pragma unroll
        for (int nf = 0; nf < 4; nf++) {
          int col = n0 + wn + nf * 16 + lr;
          float g = accg[mf][nf][j];
          float u = accu[mf][nf][j];
          float h = g / (1.f + expf(-g)) * u;
          hidden[hbase + col] = f2bf(h);
        }
      }
    }
  }
}

__global__ __launch_bounds__(256) void k_down_v1(
    const unsigned short* __restrict__ hidden, const float* __restrict__ wd,
    const int* __restrict__ counts, const int* __restrict__ offsets,
    const int* __restrict__ slot_tok, const float* __restrict__ slot_w,
    float* __restrict__ out) {
  const int e = blockIdx.z;
  const int cnt = counts[e];
  const int m0 = blockIdx.y * 128;
  if (m0 >= cnt) return;
  const int n0 = blockIdx.x * 128;
  const int base = offsets[e];

  __shared__ unsigned short As[128 * 40];
  __shared__ unsigned short Bs[128 * 40];

  const int tid = threadIdx.x;
  const int wave = tid >> 6;
  const int lane = tid & 63;
  const int wm = (wave >> 1) * 64;
  const int wn = (wave & 1) * 64;
  const int lr = lane & 15;
  const int lk = lane >> 4;
  const int r_sub = tid >> 3;
  const int kq = (tid & 7) * 4;

  const unsigned short* ap[4];
  const float* bp[4];
#pragma unroll
  for (int p = 0; p < 4; p++) {
    int row = p * 32 + r_sub;
    int gr = m0 + row;
    if (gr > cnt - 1) gr = cnt - 1;
    ap[p] = hidden + (size_t)(base + gr) * I_DIM + kq;
    bp[p] = wd + (size_t)e * H_DIM * I_DIM + (size_t)(n0 + row) * I_DIM + kq;
  }

  f32x4 acc[4][4];
#pragma unroll
  for (int i = 0; i < 4; i++)
#pragma unroll
    for (int j = 0; j < 4; j++) acc[i][j] = (f32x4){0.f, 0.f, 0.f, 0.f};

  for (int k0 = 0; k0 < I_DIM; k0 += 32) {
#pragma unroll
    for (int p = 0; p < 4; p++) {
      int row = p * 32 + r_sub;
      *reinterpret_cast<ushort4*>(&As[row * 40 + kq]) =
          *reinterpret_cast<const ushort4*>(ap[p] + k0);
      cvt_store4(&Bs[row * 40 + kq], bp[p] + k0);
    }
    __syncthreads();
    bf16x8 af[4];
#pragma unroll
    for (int mf = 0; mf < 4; mf++)
      af[mf] = *reinterpret_cast<const bf16x8*>(&As[(wm + mf * 16 + lr) * 40 + lk * 8]);
#pragma unroll
    for (int nf = 0; nf < 4; nf++) {
      bf16x8 bf = *reinterpret_cast<const bf16x8*>(&Bs[(wn + nf * 16 + lr) * 40 + lk * 8]);
#pragma unroll
      for (int mf = 0; mf < 4; mf++)
        acc[mf][nf] = __builtin_amdgcn_mfma_f32_16x16x32_bf16(af[mf], bf, acc[mf][nf], 0, 0, 0);
    }
    __syncthreads();
  }

#pragma unroll
  for (int mf = 0; mf < 4; mf++) {
#pragma unroll
    for (int j = 0; j < 4; j++) {
      int row = wm + mf * 16 + lk * 4 + j;
      if (m0 + row < cnt) {
        int slot = base + m0 + row;
        int t = slot_tok[slot];
        float w = slot_w[slot];
#pragma unroll
        for (int nf = 0; nf < 4; nf++) {
          int col = n0 + wn + nf * 16 + lr;
          atomicAdd(&out[(size_t)t * H_DIM + col], w * acc[mf][nf][j]);
        }
      }
    }
  }
}

extern "C" void kernel_launch(void* const* d_in, const int* in_sizes, int n_in,
                              void* d_out, int out_size, void* d_ws, size_t ws_size,
                              hipStream_t stream) {
  const float* x = (const float*)d_in[0];
  const float* gate_w = (const float*)d_in[1];
  const float* wg = (const float*)d_in[2];
  const float* wu = (const float*)d_in[3];
  const float* wd = (const float*)d_in[4];
  float* out = (float*)d_out;

  char* ws = (char*)d_ws;
  int* counts = (int*)(ws + 0);
  int* cursor = (int*)(ws + 64);
  int* offsets = (int*)(ws + 128);
  int2* tokE = (int2*)(ws + 256);
  float2* tokP = (float2*)(ws + 256 + 32768);
  int* slot_tok = (int*)(ws + 256 + 65536);
  float* slot_w = (float*)(ws + 256 + 98304);

  hipMemsetAsync(d_ws, 0, 256, stream);  // counts + cursor
  hipMemsetAsync(d_out, 0, (size_t)T_TOK * H_DIM * sizeof(float), stream);

  k_router<<<T_TOK, 64, 0, stream>>>(x, gate_w, tokE, tokP, counts);
  k_offsets<<<1, 64, 0, stream>>>(counts, offsets);
  k_scatter<<<T_TOK / 256, 256, 0, stream>>>(tokE, tokP, offsets, cursor, slot_tok, slot_w);

  // fast-path workspace layout
  const size_t OFF_XB  = 262144;                       // 8 MiB bf16 x
  const size_t OFF_HID = OFF_XB + 8388608;             // 64 MiB bf16 hidden
  const size_t OFF_WG  = OFF_HID + 67108864;           // 64 MiB bf16 wg
  const size_t OFF_WU  = OFF_WG + 67108864;            // 64 MiB bf16 wu
  const size_t NEED    = OFF_WU + 67108864;            // wd aliases OFF_WG

  if (ws_size >= NEED) {
    unsigned short* xb  = (unsigned short*)(ws + OFF_XB);
    unsigned short* hid = (unsigned short*)(ws + OFF_HID);
    unsigned short* wgb = (unsigned short*)(ws + OFF_WG);
    unsigned short* wub = (unsigned short*)(ws + OFF_WU);
    unsigned short* wdb = wgb;  // aliased: stream-serialized after k_gateup8

    k_cvt<<<2048, 256, 0, stream>>>(x, xb, T_TOK * H_DIM / 4);
    k_cvt<<<2048, 256, 0, stream>>>(wg, wgb, E_NUM * I_DIM * H_DIM / 4);
    k_cvt<<<2048, 256, 0, stream>>>(wu, wub, E_NUM * I_DIM * H_DIM / 4);
    k_gateup8<<<dim3(I_DIM / 128, 16, E_NUM), 512, 0, stream>>>(
        xb, wgb, wub, counts, offsets, slot_tok, hid);
    k_cvt<<<2048, 256, 0, stream>>>(wd, wdb, E_NUM * H_DIM * I_DIM / 4);
    k_down8<<<dim3(H_DIM / 128, 16, E_NUM), 512, 0, stream>>>(
        hid, wdb, counts, offsets, slot_tok, slot_w, out);
  } else {
    unsigned short* hid = (unsigned short*)(ws + 131328);
    k_gateup_v1<<<dim3(I_DIM / 128, 32, E_NUM), 256, 0, stream>>>(
        x, wg, wu, counts, offsets, slot_tok, hid);
    k_down_v1<<<dim3(H_DIM / 128, 32, E_NUM), 256, 0, stream>>>(
        hid, wd, counts, offsets, slot_tok, slot_w, out);
  }
}

// Round 4
// 642.333 us; speedup vs baseline: 1.0825x; 1.0825x over previous
//
#include <hip/hip_runtime.h>
#include <math.h>

#define T_TOK 4096
#define H_DIM 1024
#define E_NUM 8
#define I_DIM 4096

typedef __attribute__((ext_vector_type(4))) float f32x4;
typedef __attribute__((ext_vector_type(8))) short bf16x8;

__device__ inline unsigned short f2bf(float f) {
  unsigned int u = __float_as_uint(f);
  u += 0x7fffu + ((u >> 16) & 1u);   // RNE (finite data only)
  return (unsigned short)(u >> 16);
}

__device__ inline void cvt_store4(unsigned short* dst, const float* src) {
  f32x4 v = *reinterpret_cast<const f32x4*>(src);
  ushort4 o;
  o.x = f2bf(v[0]); o.y = f2bf(v[1]); o.z = f2bf(v[2]); o.w = f2bf(v[3]);
  *reinterpret_cast<ushort4*>(dst) = o;
}

// async global->LDS, 16B per lane; LDS dest is wave-uniform base + lane*16
__device__ inline void gll16(const void* g, void* l) {
  __builtin_amdgcn_global_load_lds(
      (const __attribute__((address_space(1))) void*)g,
      (__attribute__((address_space(3))) void*)l, 16, 0, 0);
}

// ---------------- router: fp32 logits, exact top-2 + softmax ----------------
__global__ __launch_bounds__(64) void k_router(const float* __restrict__ x,
                                               const float* __restrict__ gw,
                                               int2* __restrict__ tokE,
                                               float2* __restrict__ tokP,
                                               int* __restrict__ counts) {
  const int t = blockIdx.x;
  const int l = threadIdx.x;
  const float* xr = x + (size_t)t * H_DIM;
  float acc[E_NUM];
#pragma unroll
  for (int e = 0; e < E_NUM; e++) acc[e] = 0.f;
  for (int h = l; h < H_DIM; h += 64) {
    float xv = xr[h];
#pragma unroll
    for (int e = 0; e < E_NUM; e++) acc[e] += xv * gw[e * H_DIM + h];
  }
#pragma unroll
  for (int e = 0; e < E_NUM; e++) {
#pragma unroll
    for (int off = 32; off > 0; off >>= 1) acc[e] += __shfl_xor(acc[e], off);
  }
  if (l == 0) {
    float v0 = -1e30f, v1 = -1e30f;
    int e0 = 0, e1 = 0;
#pragma unroll
    for (int e = 0; e < E_NUM; e++) {
      float v = acc[e];
      if (v > v0) { v1 = v0; e1 = e0; v0 = v; e0 = e; }
      else if (v > v1) { v1 = v; e1 = e; }
    }
    float ex = expf(v1 - v0);
    float p0 = 1.f / (1.f + ex);
    float p1 = ex * p0;
    tokE[t] = make_int2(e0, e1);
    tokP[t] = make_float2(p0, p1);
    atomicAdd(&counts[e0], 1);
    atomicAdd(&counts[e1], 1);
  }
}

__global__ void k_offsets(const int* __restrict__ counts, int* __restrict__ offsets) {
  if (threadIdx.x == 0 && blockIdx.x == 0) {
    int s = 0;
    for (int e = 0; e < E_NUM; e++) { offsets[e] = s; s += counts[e]; }
    offsets[E_NUM] = s;
  }
}

__global__ __launch_bounds__(256) void k_scatter(const int2* __restrict__ tokE,
                                                 const float2* __restrict__ tokP,
                                                 const int* __restrict__ offsets,
                                                 int* __restrict__ cursor,
                                                 int* __restrict__ slot_tok,
                                                 float* __restrict__ slot_w) {
  int t = blockIdx.x * 256 + threadIdx.x;
  if (t >= T_TOK) return;
  int2 e = tokE[t];
  float2 p = tokP[t];
  int pos0 = atomicAdd(&cursor[e.x], 1);
  slot_tok[offsets[e.x] + pos0] = t;
  slot_w[offsets[e.x] + pos0] = p.x;
  int pos1 = atomicAdd(&cursor[e.y], 1);
  slot_tok[offsets[e.y] + pos1] = t;
  slot_w[offsets[e.y] + pos1] = p.y;
}

// ---------------- fp32 -> bf16 bulk convert (memory-bound) ------------------
__global__ __launch_bounds__(256) void k_cvt(const float* __restrict__ src,
                                             unsigned short* __restrict__ dst,
                                             int n4) {
  int i = blockIdx.x * 256 + threadIdx.x;
  const int stride = gridDim.x * 256;
  for (; i < n4; i += stride) {
    f32x4 v = reinterpret_cast<const f32x4*>(src)[i];
    ushort4 o;
    o.x = f2bf(v[0]); o.y = f2bf(v[1]); o.z = f2bf(v[2]); o.w = f2bf(v[3]);
    reinterpret_cast<ushort4*>(dst)[i] = o;
  }
}

// ====== FAST PATH: 128x128 tiles, BK=32, LDS double-buffer, counted vmcnt ===
// 256 thr = 4 waves (2x2), wave tile 64x64. LDS per array 128x32 bf16 = 8 KiB,
// x2 buffers. Swizzle: 16B chunk c of row r stored at chunk c^(r&3); applied
// on the global SOURCE (staging) and on the ds_read address (rule #21).
// Per-tile schedule: issue next-tile loads -> vmcnt(N) -> s_barrier ->
// ds_read+MFMA -> s_barrier. Loads stay in flight across a full tile.

// pass 1: hidden = silu(Xe @ wg^T) * (Xe @ wu^T)   [dual-B]
__global__ __launch_bounds__(256, 2) void k_gateup3(
    const unsigned short* __restrict__ xb, const unsigned short* __restrict__ wgb,
    const unsigned short* __restrict__ wub, const int* __restrict__ counts,
    const int* __restrict__ offsets, const int* __restrict__ slot_tok,
    unsigned short* __restrict__ hidden) {
  const int e = blockIdx.z;
  const int cnt = counts[e];
  const int m0 = blockIdx.y * 128;
  if (m0 >= cnt) return;
  const int n0 = blockIdx.x * 128;
  const int base = offsets[e];

  __shared__ unsigned short As[2][128 * 32];
  __shared__ unsigned short Bg[2][128 * 32];
  __shared__ unsigned short Bu[2][128 * 32];

  const int tid = threadIdx.x;
  const int wave = tid >> 6;
  const int lane = tid & 63;
  const int wm = (wave >> 1) * 64;
  const int wn = (wave & 1) * 64;
  const int lr = lane & 15;
  const int lk = lane >> 4;

  // staging: per array, wave w covers rows [w*32, w*32+32) in 2 issues of 16
  // rows (1 KiB each). lane -> row offset sr=lane>>2, chunk sc=lane&3.
  const int sr = lane >> 2;            // 0..15
  const int sc = lane & 3;             // 0..3
  const int swz = ((sc ^ (sr & 3)) << 3);   // element offset of swizzled chunk

  const size_t wboff = (size_t)e * (size_t)I_DIM * H_DIM;
  const unsigned short* srcA[2];
  const unsigned short* srcBg[2];
  const unsigned short* srcBu[2];
  const int dstoff[2] = {(wave * 32) * 32, (wave * 32 + 16) * 32};
#pragma unroll
  for (int i = 0; i < 2; i++) {
    int row = wave * 32 + i * 16 + sr;
    int gr = m0 + row; if (gr > cnt - 1) gr = cnt - 1;
    srcA[i]  = xb + (size_t)slot_tok[base + gr] * H_DIM + swz;
    srcBg[i] = wgb + wboff + (size_t)(n0 + row) * H_DIM + swz;
    srcBu[i] = wub + wboff + (size_t)(n0 + row) * H_DIM + swz;
  }

  f32x4 accg[4][4], accu[4][4];
#pragma unroll
  for (int i = 0; i < 4; i++)
#pragma unroll
    for (int j = 0; j < 4; j++) {
      accg[i][j] = (f32x4){0.f, 0.f, 0.f, 0.f};
      accu[i][j] = (f32x4){0.f, 0.f, 0.f, 0.f};
    }

  const int koff = ((lk ^ (lr & 3)) << 3);   // read-side swizzled chunk

  // drain any init-time loads so the vmcnt ledger is exact
  asm volatile("s_waitcnt vmcnt(0)" ::: "memory");

  // prologue: tile 0 -> buffer 0 (6 issues/thread, canonical order)
  gll16(srcBg[0], &Bg[0][dstoff[0]]);
  gll16(srcBg[1], &Bg[0][dstoff[1]]);
  gll16(srcBu[0], &Bu[0][dstoff[0]]);
  gll16(srcBu[1], &Bu[0][dstoff[1]]);
  gll16(srcA[0],  &As[0][dstoff[0]]);
  gll16(srcA[1],  &As[0][dstoff[1]]);

  const int NT = H_DIM / 32;   // 32
  for (int t = 0; t < NT; t++) {
    const int bb = t & 1;
    const int nb = bb ^ 1;
    const int kn = (t + 1 < NT) ? (t + 1) * 32 : 0;  // wrap: dummy in-bounds
    // issue next tile (6) -> 12 outstanding; wait to 6 = current tile landed
    gll16(srcBg[0] + kn, &Bg[nb][dstoff[0]]);
    gll16(srcBg[1] + kn, &Bg[nb][dstoff[1]]);
    gll16(srcBu[0] + kn, &Bu[nb][dstoff[0]]);
    gll16(srcBu[1] + kn, &Bu[nb][dstoff[1]]);
    gll16(srcA[0] + kn,  &As[nb][dstoff[0]]);
    gll16(srcA[1] + kn,  &As[nb][dstoff[1]]);
    asm volatile("s_waitcnt vmcnt(6)" ::: "memory");
    __builtin_amdgcn_s_barrier();

    bf16x8 af[4];
#pragma unroll
    for (int mf = 0; mf < 4; mf++)
      af[mf] = *reinterpret_cast<const bf16x8*>(&As[bb][(wm + mf * 16 + lr) * 32 + koff]);
    __builtin_amdgcn_s_setprio(1);
#pragma unroll
    for (int nf = 0; nf < 4; nf++) {
      const int ro = (wn + nf * 16 + lr) * 32 + koff;
      bf16x8 bg = *reinterpret_cast<const bf16x8*>(&Bg[bb][ro]);
      bf16x8 bu = *reinterpret_cast<const bf16x8*>(&Bu[bb][ro]);
#pragma unroll
      for (int mf = 0; mf < 4; mf++) {
        accg[mf][nf] = __builtin_amdgcn_mfma_f32_16x16x32_bf16(af[mf], bg, accg[mf][nf], 0, 0, 0);
        accu[mf][nf] = __builtin_amdgcn_mfma_f32_16x16x32_bf16(af[mf], bu, accu[mf][nf], 0, 0, 0);
      }
    }
    __builtin_amdgcn_s_setprio(0);
    __builtin_amdgcn_s_barrier();
  }
  asm volatile("s_waitcnt vmcnt(0)" ::: "memory");  // drain dummy prefetch

  // epilogue: h = silu(g) * u, store bf16
#pragma unroll
  for (int mf = 0; mf < 4; mf++) {
#pragma unroll
    for (int j = 0; j < 4; j++) {
      int row = wm + mf * 16 + lk * 4 + j;
      if (m0 + row < cnt) {
        size_t hbase = (size_t)(base + m0 + row) * I_DIM;
#pragma unroll
        for (int nf = 0; nf < 4; nf++) {
          int col = n0 + wn + nf * 16 + lr;
          float g = accg[mf][nf][j];
          float u = accu[mf][nf][j];
          hidden[hbase + col] = f2bf(g / (1.f + expf(-g)) * u);
        }
      }
    }
  }
}

// pass 2: out[t] += w * (hidden_row @ wd^T)   [single-B, K=I=4096]
__global__ __launch_bounds__(256, 2) void k_down3(
    const unsigned short* __restrict__ hidden, const unsigned short* __restrict__ wdb,
    const int* __restrict__ counts, const int* __restrict__ offsets,
    const int* __restrict__ slot_tok, const float* __restrict__ slot_w,
    float* __restrict__ out) {
  const int e = blockIdx.z;
  const int cnt = counts[e];
  const int m0 = blockIdx.y * 128;
  if (m0 >= cnt) return;
  const int n0 = blockIdx.x * 128;
  const int base = offsets[e];

  __shared__ unsigned short As[2][128 * 32];
  __shared__ unsigned short Bs[2][128 * 32];

  const int tid = threadIdx.x;
  const int wave = tid >> 6;
  const int lane = tid & 63;
  const int wm = (wave >> 1) * 64;
  const int wn = (wave & 1) * 64;
  const int lr = lane & 15;
  const int lk = lane >> 4;

  const int sr = lane >> 2;
  const int sc = lane & 3;
  const int swz = ((sc ^ (sr & 3)) << 3);

  const unsigned short* srcA[2];
  const unsigned short* srcB[2];
  const int dstoff[2] = {(wave * 32) * 32, (wave * 32 + 16) * 32};
#pragma unroll
  for (int i = 0; i < 2; i++) {
    int row = wave * 32 + i * 16 + sr;
    int gr = m0 + row; if (gr > cnt - 1) gr = cnt - 1;
    srcA[i] = hidden + (size_t)(base + gr) * I_DIM + swz;
    srcB[i] = wdb + (size_t)e * H_DIM * I_DIM + (size_t)(n0 + row) * I_DIM + swz;
  }

  f32x4 acc[4][4];
#pragma unroll
  for (int i = 0; i < 4; i++)
#pragma unroll
    for (int j = 0; j < 4; j++) acc[i][j] = (f32x4){0.f, 0.f, 0.f, 0.f};

  const int koff = ((lk ^ (lr & 3)) << 3);

  asm volatile("s_waitcnt vmcnt(0)" ::: "memory");

  gll16(srcB[0], &Bs[0][dstoff[0]]);
  gll16(srcB[1], &Bs[0][dstoff[1]]);
  gll16(srcA[0], &As[0][dstoff[0]]);
  gll16(srcA[1], &As[0][dstoff[1]]);

  const int NT = I_DIM / 32;   // 128
  for (int t = 0; t < NT; t++) {
    const int bb = t & 1;
    const int nb = bb ^ 1;
    const int kn = (t + 1 < NT) ? (t + 1) * 32 : 0;
    gll16(srcB[0] + kn, &Bs[nb][dstoff[0]]);
    gll16(srcB[1] + kn, &Bs[nb][dstoff[1]]);
    gll16(srcA[0] + kn, &As[nb][dstoff[0]]);
    gll16(srcA[1] + kn, &As[nb][dstoff[1]]);
    asm volatile("s_waitcnt vmcnt(4)" ::: "memory");
    __builtin_amdgcn_s_barrier();

    bf16x8 af[4];
#pragma unroll
    for (int mf = 0; mf < 4; mf++)
      af[mf] = *reinterpret_cast<const bf16x8*>(&As[bb][(wm + mf * 16 + lr) * 32 + koff]);
    __builtin_amdgcn_s_setprio(1);
#pragma unroll
    for (int nf = 0; nf < 4; nf++) {
      bf16x8 bf = *reinterpret_cast<const bf16x8*>(&Bs[bb][(wn + nf * 16 + lr) * 32 + koff]);
#pragma unroll
      for (int mf = 0; mf < 4; mf++)
        acc[mf][nf] = __builtin_amdgcn_mfma_f32_16x16x32_bf16(af[mf], bf, acc[mf][nf], 0, 0, 0);
    }
    __builtin_amdgcn_s_setprio(0);
    __builtin_amdgcn_s_barrier();
  }
  asm volatile("s_waitcnt vmcnt(0)" ::: "memory");

#pragma unroll
  for (int mf = 0; mf < 4; mf++) {
#pragma unroll
    for (int j = 0; j < 4; j++) {
      int row = wm + mf * 16 + lk * 4 + j;
      if (m0 + row < cnt) {
        int slot = base + m0 + row;
        int t = slot_tok[slot];
        float w = slot_w[slot];
#pragma unroll
        for (int nf = 0; nf < 4; nf++) {
          int col = n0 + wn + nf * 16 + lr;
          atomicAdd(&out[(size_t)t * H_DIM + col], w * acc[mf][nf][j]);
        }
      }
    }
  }
}

// ================= FALLBACK PATH (fp32 in-loop convert, proven) =============
__global__ __launch_bounds__(256) void k_gateup_v1(
    const float* __restrict__ x, const float* __restrict__ wg,
    const float* __restrict__ wu, const int* __restrict__ counts,
    const int* __restrict__ offsets, const int* __restrict__ slot_tok,
    unsigned short* __restrict__ hidden) {
  const int e = blockIdx.z;
  const int cnt = counts[e];
  const int m0 = blockIdx.y * 128;
  if (m0 >= cnt) return;
  const int n0 = blockIdx.x * 128;
  const int base = offsets[e];

  __shared__ unsigned short As[128 * 40];
  __shared__ unsigned short Bgs[128 * 40];
  __shared__ unsigned short Bus[128 * 40];

  const int tid = threadIdx.x;
  const int wave = tid >> 6;
  const int lane = tid & 63;
  const int wm = (wave >> 1) * 64;
  const int wn = (wave & 1) * 64;
  const int lr = lane & 15;
  const int lk = lane >> 4;
  const int r_sub = tid >> 3;
  const int kq = (tid & 7) * 4;

  const float* wge = wg + (size_t)e * I_DIM * H_DIM;
  const float* wue = wu + (size_t)e * I_DIM * H_DIM;

  const float* aptr[4];
  const float* bgptr[4];
  const float* buptr[4];
#pragma unroll
  for (int p = 0; p < 4; p++) {
    int row = p * 32 + r_sub;
    int gr = m0 + row;
    if (gr > cnt - 1) gr = cnt - 1;
    aptr[p] = x + (size_t)slot_tok[base + gr] * H_DIM + kq;
    bgptr[p] = wge + (size_t)(n0 + row) * H_DIM + kq;
    buptr[p] = wue + (size_t)(n0 + row) * H_DIM + kq;
  }

  f32x4 accg[4][4], accu[4][4];
#pragma unroll
  for (int i = 0; i < 4; i++)
#pragma unroll
    for (int j = 0; j < 4; j++) {
      accg[i][j] = (f32x4){0.f, 0.f, 0.f, 0.f};
      accu[i][j] = (f32x4){0.f, 0.f, 0.f, 0.f};
    }

  for (int k0 = 0; k0 < H_DIM; k0 += 32) {
#pragma unroll
    for (int p = 0; p < 4; p++) {
      int row = p * 32 + r_sub;
      cvt_store4(&As[row * 40 + kq], aptr[p] + k0);
      cvt_store4(&Bgs[row * 40 + kq], bgptr[p] + k0);
      cvt_store4(&Bus[row * 40 + kq], buptr[p] + k0);
    }
    __syncthreads();
    bf16x8 af[4];
#pragma unroll
    for (int mf = 0; mf < 4; mf++)
      af[mf] = *reinterpret_cast<const bf16x8*>(&As[(wm + mf * 16 + lr) * 40 + lk * 8]);
#pragma unroll
    for (int nf = 0; nf < 4; nf++) {
      bf16x8 bg = *reinterpret_cast<const bf16x8*>(&Bgs[(wn + nf * 16 + lr) * 40 + lk * 8]);
      bf16x8 bu = *reinterpret_cast<const bf16x8*>(&Bus[(wn + nf * 16 + lr) * 40 + lk * 8]);
#pragma unroll
      for (int mf = 0; mf < 4; mf++) {
        accg[mf][nf] = __builtin_amdgcn_mfma_f32_16x16x32_bf16(af[mf], bg, accg[mf][nf], 0, 0, 0);
        accu[mf][nf] = __builtin_amdgcn_mfma_f32_16x16x32_bf16(af[mf], bu, accu[mf][nf], 0, 0, 0);
      }
    }
    __syncthreads();
  }

#pragma unroll
  for (int mf = 0; mf < 4; mf++) {
#pragma unroll
    for (int j = 0; j < 4; j++) {
      int row = wm + mf * 16 + lk * 4 + j;
      if (m0 + row < cnt) {
        size_t hbase = (size_t)(base + m0 + row) * I_DIM;
#pragma unroll
        for (int nf = 0; nf < 4; nf++) {
          int col = n0 + wn + nf * 16 + lr;
          float g = accg[mf][nf][j];
          float u = accu[mf][nf][j];
          float h = g / (1.f + expf(-g)) * u;
          hidden[hbase + col] = f2bf(h);
        }
      }
    }
  }
}

__global__ __launch_bounds__(256) void k_down_v1(
    const unsigned short* __restrict__ hidden, const float* __restrict__ wd,
    const int* __restrict__ counts, const int* __restrict__ offsets,
    const int* __restrict__ slot_tok, const float* __restrict__ slot_w,
    float* __restrict__ out) {
  const int e = blockIdx.z;
  const int cnt = counts[e];
  const int m0 = blockIdx.y * 128;
  if (m0 >= cnt) return;
  const int n0 = blockIdx.x * 128;
  const int base = offsets[e];

  __shared__ unsigned short As[128 * 40];
  __shared__ unsigned short Bs[128 * 40];

  const int tid = threadIdx.x;
  const int wave = tid >> 6;
  const int lane = tid & 63;
  const int wm = (wave >> 1) * 64;
  const int wn = (wave & 1) * 64;
  const int lr = lane & 15;
  const int lk = lane >> 4;
  const int r_sub = tid >> 3;
  const int kq = (tid & 7) * 4;

  const unsigned short* ap[4];
  const float* bp[4];
#pragma unroll
  for (int p = 0; p < 4; p++) {
    int row = p * 32 + r_sub;
    int gr = m0 + row;
    if (gr > cnt - 1) gr = cnt - 1;
    ap[p] = hidden + (size_t)(base + gr) * I_DIM + kq;
    bp[p] = wd + (size_t)e * H_DIM * I_DIM + (size_t)(n0 + row) * I_DIM + kq;
  }

  f32x4 acc[4][4];
#pragma unroll
  for (int i = 0; i < 4; i++)
#pragma unroll
    for (int j = 0; j < 4; j++) acc[i][j] = (f32x4){0.f, 0.f, 0.f, 0.f};

  for (int k0 = 0; k0 < I_DIM; k0 += 32) {
#pragma unroll
    for (int p = 0; p < 4; p++) {
      int row = p * 32 + r_sub;
      *reinterpret_cast<ushort4*>(&As[row * 40 + kq]) =
          *reinterpret_cast<const ushort4*>(ap[p] + k0);
      cvt_store4(&Bs[row * 40 + kq], bp[p] + k0);
    }
    __syncthreads();
    bf16x8 af[4];
#pragma unroll
    for (int mf = 0; mf < 4; mf++)
      af[mf] = *reinterpret_cast<const bf16x8*>(&As[(wm + mf * 16 + lr) * 40 + lk * 8]);
#pragma unroll
    for (int nf = 0; nf < 4; nf++) {
      bf16x8 bf = *reinterpret_cast<const bf16x8*>(&Bs[(wn + nf * 16 + lr) * 40 + lk * 8]);
#pragma unroll
      for (int mf = 0; mf < 4; mf++)
        acc[mf][nf] = __builtin_amdgcn_mfma_f32_16x16x32_bf16(af[mf], bf, acc[mf][nf], 0, 0, 0);
    }
    __syncthreads();
  }

#pragma unroll
  for (int mf = 0; mf < 4; mf++) {
#pragma unroll
    for (int j = 0; j < 4; j++) {
      int row = wm + mf * 16 + lk * 4 + j;
      if (m0 + row < cnt) {
        int slot = base + m0 + row;
        int t = slot_tok[slot];
        float w = slot_w[slot];
#pragma unroll
        for (int nf = 0; nf < 4; nf++) {
          int col = n0 + wn + nf * 16 + lr;
          atomicAdd(&out[(size_t)t * H_DIM + col], w * acc[mf][nf][j]);
        }
      }
    }
  }
}

extern "C" void kernel_launch(void* const* d_in, const int* in_sizes, int n_in,
                              void* d_out, int out_size, void* d_ws, size_t ws_size,
                              hipStream_t stream) {
  const float* x = (const float*)d_in[0];
  const float* gate_w = (const float*)d_in[1];
  const float* wg = (const float*)d_in[2];
  const float* wu = (const float*)d_in[3];
  const float* wd = (const float*)d_in[4];
  float* out = (float*)d_out;

  char* ws = (char*)d_ws;
  int* counts = (int*)(ws + 0);
  int* cursor = (int*)(ws + 64);
  int* offsets = (int*)(ws + 128);
  int2* tokE = (int2*)(ws + 256);
  float2* tokP = (float2*)(ws + 256 + 32768);
  int* slot_tok = (int*)(ws + 256 + 65536);
  float* slot_w = (float*)(ws + 256 + 98304);

  hipMemsetAsync(d_ws, 0, 256, stream);  // counts + cursor
  hipMemsetAsync(d_out, 0, (size_t)T_TOK * H_DIM * sizeof(float), stream);

  k_router<<<T_TOK, 64, 0, stream>>>(x, gate_w, tokE, tokP, counts);
  k_offsets<<<1, 64, 0, stream>>>(counts, offsets);
  k_scatter<<<T_TOK / 256, 256, 0, stream>>>(tokE, tokP, offsets, cursor, slot_tok, slot_w);

  // fast-path workspace layout
  const size_t OFF_XB  = 262144;                       // 8 MiB bf16 x
  const size_t OFF_HID = OFF_XB + 8388608;             // 64 MiB bf16 hidden
  const size_t OFF_WG  = OFF_HID + 67108864;           // 64 MiB bf16 wg
  const size_t OFF_WU  = OFF_WG + 67108864;            // 64 MiB bf16 wu
  const size_t NEED    = OFF_WU + 67108864;            // wd aliases OFF_WG

  if (ws_size >= NEED) {
    unsigned short* xb  = (unsigned short*)(ws + OFF_XB);
    unsigned short* hid = (unsigned short*)(ws + OFF_HID);
    unsigned short* wgb = (unsigned short*)(ws + OFF_WG);
    unsigned short* wub = (unsigned short*)(ws + OFF_WU);
    unsigned short* wdb = wgb;  // aliased: stream-serialized after k_gateup3

    k_cvt<<<2048, 256, 0, stream>>>(x, xb, T_TOK * H_DIM / 4);
    k_cvt<<<2048, 256, 0, stream>>>(wg, wgb, E_NUM * I_DIM * H_DIM / 4);
    k_cvt<<<2048, 256, 0, stream>>>(wu, wub, E_NUM * I_DIM * H_DIM / 4);
    k_gateup3<<<dim3(I_DIM / 128, 32, E_NUM), 256, 0, stream>>>(
        xb, wgb, wub, counts, offsets, slot_tok, hid);
    k_cvt<<<2048, 256, 0, stream>>>(wd, wdb, E_NUM * H_DIM * I_DIM / 4);
    k_down3<<<dim3(H_DIM / 128, 32, E_NUM), 256, 0, stream>>>(
        hid, wdb, counts, offsets, slot_tok, slot_w, out);
  } else {
    unsigned short* hid = (unsigned short*)(ws + 131328);
    k_gateup_v1<<<dim3(I_DIM / 128, 32, E_NUM), 256, 0, stream>>>(
        x, wg, wu, counts, offsets, slot_tok, hid);
    k_down_v1<<<dim3(H_DIM / 128, 32, E_NUM), 256, 0, stream>>>(
        hid, wd, counts, offsets, slot_tok, slot_w, out);
  }
}

// Round 5
// 640.261 us; speedup vs baseline: 1.0860x; 1.0032x over previous
//
#include <hip/hip_runtime.h>
#include <math.h>

#define T_TOK 4096
#define H_DIM 1024
#define E_NUM 8
#define I_DIM 4096

typedef __attribute__((ext_vector_type(4))) float f32x4;
typedef __attribute__((ext_vector_type(8))) short bf16x8;

__device__ inline unsigned short f2bf(float f) {
  unsigned int u = __float_as_uint(f);
  u += 0x7fffu + ((u >> 16) & 1u);   // RNE (finite data only)
  return (unsigned short)(u >> 16);
}

__device__ inline void cvt_store4(unsigned short* dst, const float* src) {
  f32x4 v = *reinterpret_cast<const f32x4*>(src);
  ushort4 o;
  o.x = f2bf(v[0]); o.y = f2bf(v[1]); o.z = f2bf(v[2]); o.w = f2bf(v[3]);
  *reinterpret_cast<ushort4*>(dst) = o;
}

// async global->LDS, 16B per lane; LDS dest is wave-uniform base + lane*16
__device__ inline void gll16(const void* g, void* l) {
  __builtin_amdgcn_global_load_lds(
      (const __attribute__((address_space(1))) void*)g,
      (__attribute__((address_space(3))) void*)l, 16, 0, 0);
}

// ---------------- router: fp32 logits, exact top-2 + softmax ----------------
__global__ __launch_bounds__(64) void k_router(const float* __restrict__ x,
                                               const float* __restrict__ gw,
                                               int2* __restrict__ tokE,
                                               float2* __restrict__ tokP,
                                               int* __restrict__ counts) {
  const int t = blockIdx.x;
  const int l = threadIdx.x;
  const float* xr = x + (size_t)t * H_DIM;
  float acc[E_NUM];
#pragma unroll
  for (int e = 0; e < E_NUM; e++) acc[e] = 0.f;
  for (int h = l; h < H_DIM; h += 64) {
    float xv = xr[h];
#pragma unroll
    for (int e = 0; e < E_NUM; e++) acc[e] += xv * gw[e * H_DIM + h];
  }
#pragma unroll
  for (int e = 0; e < E_NUM; e++) {
#pragma unroll
    for (int off = 32; off > 0; off >>= 1) acc[e] += __shfl_xor(acc[e], off);
  }
  if (l == 0) {
    float v0 = -1e30f, v1 = -1e30f;
    int e0 = 0, e1 = 0;
#pragma unroll
    for (int e = 0; e < E_NUM; e++) {
      float v = acc[e];
      if (v > v0) { v1 = v0; e1 = e0; v0 = v; e0 = e; }
      else if (v > v1) { v1 = v; e1 = e; }
    }
    float ex = expf(v1 - v0);
    float p0 = 1.f / (1.f + ex);
    float p1 = ex * p0;
    tokE[t] = make_int2(e0, e1);
    tokP[t] = make_float2(p0, p1);
    atomicAdd(&counts[e0], 1);
    atomicAdd(&counts[e1], 1);
  }
}

__global__ void k_offsets(const int* __restrict__ counts, int* __restrict__ offsets) {
  if (threadIdx.x == 0 && blockIdx.x == 0) {
    int s = 0;
    for (int e = 0; e < E_NUM; e++) { offsets[e] = s; s += counts[e]; }
    offsets[E_NUM] = s;
  }
}

__global__ __launch_bounds__(256) void k_scatter(const int2* __restrict__ tokE,
                                                 const float2* __restrict__ tokP,
                                                 const int* __restrict__ offsets,
                                                 int* __restrict__ cursor,
                                                 int* __restrict__ slot_tok,
                                                 float* __restrict__ slot_w) {
  int t = blockIdx.x * 256 + threadIdx.x;
  if (t >= T_TOK) return;
  int2 e = tokE[t];
  float2 p = tokP[t];
  int pos0 = atomicAdd(&cursor[e.x], 1);
  slot_tok[offsets[e.x] + pos0] = t;
  slot_w[offsets[e.x] + pos0] = p.x;
  int pos1 = atomicAdd(&cursor[e.y], 1);
  slot_tok[offsets[e.y] + pos1] = t;
  slot_w[offsets[e.y] + pos1] = p.y;
}

// ---------------- fp32 -> bf16 bulk convert (memory-bound) ------------------
__global__ __launch_bounds__(256) void k_cvt(const float* __restrict__ src,
                                             unsigned short* __restrict__ dst,
                                             int n4) {
  int i = blockIdx.x * 256 + threadIdx.x;
  const int stride = gridDim.x * 256;
  for (; i < n4; i += stride) {
    f32x4 v = reinterpret_cast<const f32x4*>(src)[i];
    ushort4 o;
    o.x = f2bf(v[0]); o.y = f2bf(v[1]); o.z = f2bf(v[2]); o.w = f2bf(v[3]);
    reinterpret_cast<ushort4*>(dst)[i] = o;
  }
}

// ====== FAST PATH: 128x128 tiles, BK=32, LDS double-buffer, counted vmcnt ===
// 256 thr = 4 waves (2x2), wave tile 64x64. LDS per array 128x32 bf16 = 8 KiB,
// x2 buffers. Swizzle (bank-exact for 64B rows): 16B chunk c of row r stored
// at chunk c ^ ((r>>1)&3). For any 8 consecutive rows at fixed lk, the 8
// ds_read_b128 lanes then cover all 32 banks exactly once (row bank base
// alternates 0/16 with row parity; row-pair index rotates the 4-chunk slot).
// Applied on the global SOURCE (staging) and the ds_read address (rule #21).
// Per-tile schedule: issue next-tile loads -> vmcnt(N) -> s_barrier ->
// ds_read+MFMA -> s_barrier. Loads stay in flight across a full tile.

// pass 1: hidden = silu(Xe @ wg^T) * (Xe @ wu^T)   [dual-B]
__global__ __launch_bounds__(256, 2) void k_gateup3(
    const unsigned short* __restrict__ xb, const unsigned short* __restrict__ wgb,
    const unsigned short* __restrict__ wub, const int* __restrict__ counts,
    const int* __restrict__ offsets, const int* __restrict__ slot_tok,
    unsigned short* __restrict__ hidden) {
  const int e = blockIdx.z;
  const int cnt = counts[e];
  const int m0 = blockIdx.y * 128;
  if (m0 >= cnt) return;
  const int n0 = blockIdx.x * 128;
  const int base = offsets[e];

  __shared__ unsigned short As[2][128 * 32];
  __shared__ unsigned short Bg[2][128 * 32];
  __shared__ unsigned short Bu[2][128 * 32];

  const int tid = threadIdx.x;
  const int wave = tid >> 6;
  const int lane = tid & 63;
  const int wm = (wave >> 1) * 64;
  const int wn = (wave & 1) * 64;
  const int lr = lane & 15;
  const int lk = lane >> 4;

  // staging: per array, wave w covers rows [w*32, w*32+32) in 2 issues of 16
  // rows (1 KiB each). lane -> row offset sr=lane>>2, chunk slot sc=lane&3.
  const int sr = lane >> 2;            // 0..15
  const int sc = lane & 3;             // 0..3
  const int swz = ((sc ^ ((sr >> 1) & 3)) << 3);  // element offset, bank-exact

  const size_t wboff = (size_t)e * (size_t)I_DIM * H_DIM;
  const unsigned short* srcA[2];
  const unsigned short* srcBg[2];
  const unsigned short* srcBu[2];
  const int dstoff[2] = {(wave * 32) * 32, (wave * 32 + 16) * 32};
#pragma unroll
  for (int i = 0; i < 2; i++) {
    int row = wave * 32 + i * 16 + sr;
    int gr = m0 + row; if (gr > cnt - 1) gr = cnt - 1;
    srcA[i]  = xb + (size_t)slot_tok[base + gr] * H_DIM + swz;
    srcBg[i] = wgb + wboff + (size_t)(n0 + row) * H_DIM + swz;
    srcBu[i] = wub + wboff + (size_t)(n0 + row) * H_DIM + swz;
  }

  f32x4 accg[4][4], accu[4][4];
#pragma unroll
  for (int i = 0; i < 4; i++)
#pragma unroll
    for (int j = 0; j < 4; j++) {
      accg[i][j] = (f32x4){0.f, 0.f, 0.f, 0.f};
      accu[i][j] = (f32x4){0.f, 0.f, 0.f, 0.f};
    }

  const int koff = ((lk ^ ((lr >> 1) & 3)) << 3);   // read-side, same involution

  // drain any init-time loads so the vmcnt ledger is exact
  asm volatile("s_waitcnt vmcnt(0)" ::: "memory");

  // prologue: tile 0 -> buffer 0 (6 issues/thread, canonical order)
  gll16(srcBg[0], &Bg[0][dstoff[0]]);
  gll16(srcBg[1], &Bg[0][dstoff[1]]);
  gll16(srcBu[0], &Bu[0][dstoff[0]]);
  gll16(srcBu[1], &Bu[0][dstoff[1]]);
  gll16(srcA[0],  &As[0][dstoff[0]]);
  gll16(srcA[1],  &As[0][dstoff[1]]);

  const int NT = H_DIM / 32;   // 32
  for (int t = 0; t < NT; t++) {
    const int bb = t & 1;
    const int nb = bb ^ 1;
    const int kn = (t + 1 < NT) ? (t + 1) * 32 : 0;  // wrap: dummy in-bounds
    // issue next tile (6) -> 12 outstanding; wait to 6 = current tile landed
    gll16(srcBg[0] + kn, &Bg[nb][dstoff[0]]);
    gll16(srcBg[1] + kn, &Bg[nb][dstoff[1]]);
    gll16(srcBu[0] + kn, &Bu[nb][dstoff[0]]);
    gll16(srcBu[1] + kn, &Bu[nb][dstoff[1]]);
    gll16(srcA[0] + kn,  &As[nb][dstoff[0]]);
    gll16(srcA[1] + kn,  &As[nb][dstoff[1]]);
    asm volatile("s_waitcnt vmcnt(6)" ::: "memory");
    __builtin_amdgcn_s_barrier();

    bf16x8 af[4];
#pragma unroll
    for (int mf = 0; mf < 4; mf++)
      af[mf] = *reinterpret_cast<const bf16x8*>(&As[bb][(wm + mf * 16 + lr) * 32 + koff]);
    __builtin_amdgcn_s_setprio(1);
#pragma unroll
    for (int nf = 0; nf < 4; nf++) {
      const int ro = (wn + nf * 16 + lr) * 32 + koff;
      bf16x8 bg = *reinterpret_cast<const bf16x8*>(&Bg[bb][ro]);
      bf16x8 bu = *reinterpret_cast<const bf16x8*>(&Bu[bb][ro]);
#pragma unroll
      for (int mf = 0; mf < 4; mf++) {
        accg[mf][nf] = __builtin_amdgcn_mfma_f32_16x16x32_bf16(af[mf], bg, accg[mf][nf], 0, 0, 0);
        accu[mf][nf] = __builtin_amdgcn_mfma_f32_16x16x32_bf16(af[mf], bu, accu[mf][nf], 0, 0, 0);
      }
    }
    __builtin_amdgcn_s_setprio(0);
    __builtin_amdgcn_s_barrier();
  }
  asm volatile("s_waitcnt vmcnt(0)" ::: "memory");  // drain dummy prefetch

  // epilogue: h = silu(g) * u, store bf16
#pragma unroll
  for (int mf = 0; mf < 4; mf++) {
#pragma unroll
    for (int j = 0; j < 4; j++) {
      int row = wm + mf * 16 + lk * 4 + j;
      if (m0 + row < cnt) {
        size_t hbase = (size_t)(base + m0 + row) * I_DIM;
#pragma unroll
        for (int nf = 0; nf < 4; nf++) {
          int col = n0 + wn + nf * 16 + lr;
          float g = accg[mf][nf][j];
          float u = accu[mf][nf][j];
          hidden[hbase + col] = f2bf(g / (1.f + expf(-g)) * u);
        }
      }
    }
  }
}

// pass 2: out[t] += w * (hidden_row @ wd^T)   [single-B, K=I=4096]
__global__ __launch_bounds__(256, 2) void k_down3(
    const unsigned short* __restrict__ hidden, const unsigned short* __restrict__ wdb,
    const int* __restrict__ counts, const int* __restrict__ offsets,
    const int* __restrict__ slot_tok, const float* __restrict__ slot_w,
    float* __restrict__ out) {
  const int e = blockIdx.z;
  const int cnt = counts[e];
  const int m0 = blockIdx.y * 128;
  if (m0 >= cnt) return;
  const int n0 = blockIdx.x * 128;
  const int base = offsets[e];

  __shared__ unsigned short As[2][128 * 32];
  __shared__ unsigned short Bs[2][128 * 32];

  const int tid = threadIdx.x;
  const int wave = tid >> 6;
  const int lane = tid & 63;
  const int wm = (wave >> 1) * 64;
  const int wn = (wave & 1) * 64;
  const int lr = lane & 15;
  const int lk = lane >> 4;

  const int sr = lane >> 2;
  const int sc = lane & 3;
  const int swz = ((sc ^ ((sr >> 1) & 3)) << 3);

  const unsigned short* srcA[2];
  const unsigned short* srcB[2];
  const int dstoff[2] = {(wave * 32) * 32, (wave * 32 + 16) * 32};
#pragma unroll
  for (int i = 0; i < 2; i++) {
    int row = wave * 32 + i * 16 + sr;
    int gr = m0 + row; if (gr > cnt - 1) gr = cnt - 1;
    srcA[i] = hidden + (size_t)(base + gr) * I_DIM + swz;
    srcB[i] = wdb + (size_t)e * H_DIM * I_DIM + (size_t)(n0 + row) * I_DIM + swz;
  }

  f32x4 acc[4][4];
#pragma unroll
  for (int i = 0; i < 4; i++)
#pragma unroll
    for (int j = 0; j < 4; j++) acc[i][j] = (f32x4){0.f, 0.f, 0.f, 0.f};

  const int koff = ((lk ^ ((lr >> 1) & 3)) << 3);

  asm volatile("s_waitcnt vmcnt(0)" ::: "memory");

  gll16(srcB[0], &Bs[0][dstoff[0]]);
  gll16(srcB[1], &Bs[0][dstoff[1]]);
  gll16(srcA[0], &As[0][dstoff[0]]);
  gll16(srcA[1], &As[0][dstoff[1]]);

  const int NT = I_DIM / 32;   // 128
  for (int t = 0; t < NT; t++) {
    const int bb = t & 1;
    const int nb = bb ^ 1;
    const int kn = (t + 1 < NT) ? (t + 1) * 32 : 0;
    gll16(srcB[0] + kn, &Bs[nb][dstoff[0]]);
    gll16(srcB[1] + kn, &Bs[nb][dstoff[1]]);
    gll16(srcA[0] + kn, &As[nb][dstoff[0]]);
    gll16(srcA[1] + kn, &As[nb][dstoff[1]]);
    asm volatile("s_waitcnt vmcnt(4)" ::: "memory");
    __builtin_amdgcn_s_barrier();

    bf16x8 af[4];
#pragma unroll
    for (int mf = 0; mf < 4; mf++)
      af[mf] = *reinterpret_cast<const bf16x8*>(&As[bb][(wm + mf * 16 + lr) * 32 + koff]);
    __builtin_amdgcn_s_setprio(1);
#pragma unroll
    for (int nf = 0; nf < 4; nf++) {
      bf16x8 bf = *reinterpret_cast<const bf16x8*>(&Bs[bb][(wn + nf * 16 + lr) * 32 + koff]);
#pragma unroll
      for (int mf = 0; mf < 4; mf++)
        acc[mf][nf] = __builtin_amdgcn_mfma_f32_16x16x32_bf16(af[mf], bf, acc[mf][nf], 0, 0, 0);
    }
    __builtin_amdgcn_s_setprio(0);
    __builtin_amdgcn_s_barrier();
  }
  asm volatile("s_waitcnt vmcnt(0)" ::: "memory");

#pragma unroll
  for (int mf = 0; mf < 4; mf++) {
#pragma unroll
    for (int j = 0; j < 4; j++) {
      int row = wm + mf * 16 + lk * 4 + j;
      if (m0 + row < cnt) {
        int slot = base + m0 + row;
        int t = slot_tok[slot];
        float w = slot_w[slot];
#pragma unroll
        for (int nf = 0; nf < 4; nf++) {
          int col = n0 + wn + nf * 16 + lr;
          atomicAdd(&out[(size_t)t * H_DIM + col], w * acc[mf][nf][j]);
        }
      }
    }
  }
}

// ================= FALLBACK PATH (fp32 in-loop convert, proven) =============
__global__ __launch_bounds__(256) void k_gateup_v1(
    const float* __restrict__ x, const float* __restrict__ wg,
    const float* __restrict__ wu, const int* __restrict__ counts,
    const int* __restrict__ offsets, const int* __restrict__ slot_tok,
    unsigned short* __restrict__ hidden) {
  const int e = blockIdx.z;
  const int cnt = counts[e];
  const int m0 = blockIdx.y * 128;
  if (m0 >= cnt) return;
  const int n0 = blockIdx.x * 128;
  const int base = offsets[e];

  __shared__ unsigned short As[128 * 40];
  __shared__ unsigned short Bgs[128 * 40];
  __shared__ unsigned short Bus[128 * 40];

  const int tid = threadIdx.x;
  const int wave = tid >> 6;
  const int lane = tid & 63;
  const int wm = (wave >> 1) * 64;
  const int wn = (wave & 1) * 64;
  const int lr = lane & 15;
  const int lk = lane >> 4;
  const int r_sub = tid >> 3;
  const int kq = (tid & 7) * 4;

  const float* wge = wg + (size_t)e * I_DIM * H_DIM;
  const float* wue = wu + (size_t)e * I_DIM * H_DIM;

  const float* aptr[4];
  const float* bgptr[4];
  const float* buptr[4];
#pragma unroll
  for (int p = 0; p < 4; p++) {
    int row = p * 32 + r_sub;
    int gr = m0 + row;
    if (gr > cnt - 1) gr = cnt - 1;
    aptr[p] = x + (size_t)slot_tok[base + gr] * H_DIM + kq;
    bgptr[p] = wge + (size_t)(n0 + row) * H_DIM + kq;
    buptr[p] = wue + (size_t)(n0 + row) * H_DIM + kq;
  }

  f32x4 accg[4][4], accu[4][4];
#pragma unroll
  for (int i = 0; i < 4; i++)
#pragma unroll
    for (int j = 0; j < 4; j++) {
      accg[i][j] = (f32x4){0.f, 0.f, 0.f, 0.f};
      accu[i][j] = (f32x4){0.f, 0.f, 0.f, 0.f};
    }

  for (int k0 = 0; k0 < H_DIM; k0 += 32) {
#pragma unroll
    for (int p = 0; p < 4; p++) {
      int row = p * 32 + r_sub;
      cvt_store4(&As[row * 40 + kq], aptr[p] + k0);
      cvt_store4(&Bgs[row * 40 + kq], bgptr[p] + k0);
      cvt_store4(&Bus[row * 40 + kq], buptr[p] + k0);
    }
    __syncthreads();
    bf16x8 af[4];
#pragma unroll
    for (int mf = 0; mf < 4; mf++)
      af[mf] = *reinterpret_cast<const bf16x8*>(&As[(wm + mf * 16 + lr) * 40 + lk * 8]);
#pragma unroll
    for (int nf = 0; nf < 4; nf++) {
      bf16x8 bg = *reinterpret_cast<const bf16x8*>(&Bgs[(wn + nf * 16 + lr) * 40 + lk * 8]);
      bf16x8 bu = *reinterpret_cast<const bf16x8*>(&Bus[(wn + nf * 16 + lr) * 40 + lk * 8]);
#pragma unroll
      for (int mf = 0; mf < 4; mf++) {
        accg[mf][nf] = __builtin_amdgcn_mfma_f32_16x16x32_bf16(af[mf], bg, accg[mf][nf], 0, 0, 0);
        accu[mf][nf] = __builtin_amdgcn_mfma_f32_16x16x32_bf16(af[mf], bu, accu[mf][nf], 0, 0, 0);
      }
    }
    __syncthreads();
  }

#pragma unroll
  for (int mf = 0; mf < 4; mf++) {
#pragma unroll
    for (int j = 0; j < 4; j++) {
      int row = wm + mf * 16 + lk * 4 + j;
      if (m0 + row < cnt) {
        size_t hbase = (size_t)(base + m0 + row) * I_DIM;
#pragma unroll
        for (int nf = 0; nf < 4; nf++) {
          int col = n0 + wn + nf * 16 + lr;
          float g = accg[mf][nf][j];
          float u = accu[mf][nf][j];
          float h = g / (1.f + expf(-g)) * u;
          hidden[hbase + col] = f2bf(h);
        }
      }
    }
  }
}

__global__ __launch_bounds__(256) void k_down_v1(
    const unsigned short* __restrict__ hidden, const float* __restrict__ wd,
    const int* __restrict__ counts, const int* __restrict__ offsets,
    const int* __restrict__ slot_tok, const float* __restrict__ slot_w,
    float* __restrict__ out) {
  const int e = blockIdx.z;
  const int cnt = counts[e];
  const int m0 = blockIdx.y * 128;
  if (m0 >= cnt) return;
  const int n0 = blockIdx.x * 128;
  const int base = offsets[e];

  __shared__ unsigned short As[128 * 40];
  __shared__ unsigned short Bs[128 * 40];

  const int tid = threadIdx.x;
  const int wave = tid >> 6;
  const int lane = tid & 63;
  const int wm = (wave >> 1) * 64;
  const int wn = (wave & 1) * 64;
  const int lr = lane & 15;
  const int lk = lane >> 4;
  const int r_sub = tid >> 3;
  const int kq = (tid & 7) * 4;

  const unsigned short* ap[4];
  const float* bp[4];
#pragma unroll
  for (int p = 0; p < 4; p++) {
    int row = p * 32 + r_sub;
    int gr = m0 + row;
    if (gr > cnt - 1) gr = cnt - 1;
    ap[p] = hidden + (size_t)(base + gr) * I_DIM + kq;
    bp[p] = wd + (size_t)e * H_DIM * I_DIM + (size_t)(n0 + row) * I_DIM + kq;
  }

  f32x4 acc[4][4];
#pragma unroll
  for (int i = 0; i < 4; i++)
#pragma unroll
    for (int j = 0; j < 4; j++) acc[i][j] = (f32x4){0.f, 0.f, 0.f, 0.f};

  for (int k0 = 0; k0 < I_DIM; k0 += 32) {
#pragma unroll
    for (int p = 0; p < 4; p++) {
      int row = p * 32 + r_sub;
      *reinterpret_cast<ushort4*>(&As[row * 40 + kq]) =
          *reinterpret_cast<const ushort4*>(ap[p] + k0);
      cvt_store4(&Bs[row * 40 + kq], bp[p] + k0);
    }
    __syncthreads();
    bf16x8 af[4];
#pragma unroll
    for (int mf = 0; mf < 4; mf++)
      af[mf] = *reinterpret_cast<const bf16x8*>(&As[(wm + mf * 16 + lr) * 40 + lk * 8]);
#pragma unroll
    for (int nf = 0; nf < 4; nf++) {
      bf16x8 bf = *reinterpret_cast<const bf16x8*>(&Bs[(wn + nf * 16 + lr) * 40 + lk * 8]);
#pragma unroll
      for (int mf = 0; mf < 4; mf++)
        acc[mf][nf] = __builtin_amdgcn_mfma_f32_16x16x32_bf16(af[mf], bf, acc[mf][nf], 0, 0, 0);
    }
    __syncthreads();
  }

#pragma unroll
  for (int mf = 0; mf < 4; mf++) {
#pragma unroll
    for (int j = 0; j < 4; j++) {
      int row = wm + mf * 16 + lk * 4 + j;
      if (m0 + row < cnt) {
        int slot = base + m0 + row;
        int t = slot_tok[slot];
        float w = slot_w[slot];
#pragma unroll
        for (int nf = 0; nf < 4; nf++) {
          int col = n0 + wn + nf * 16 + lr;
          atomicAdd(&out[(size_t)t * H_DIM + col], w * acc[mf][nf][j]);
        }
      }
    }
  }
}

extern "C" void kernel_launch(void* const* d_in, const int* in_sizes, int n_in,
                              void* d_out, int out_size, void* d_ws, size_t ws_size,
                              hipStream_t stream) {
  const float* x = (const float*)d_in[0];
  const float* gate_w = (const float*)d_in[1];
  const float* wg = (const float*)d_in[2];
  const float* wu = (const float*)d_in[3];
  const float* wd = (const float*)d_in[4];
  float* out = (float*)d_out;

  char* ws = (char*)d_ws;
  int* counts = (int*)(ws + 0);
  int* cursor = (int*)(ws + 64);
  int* offsets = (int*)(ws + 128);
  int2* tokE = (int2*)(ws + 256);
  float2* tokP = (float2*)(ws + 256 + 32768);
  int* slot_tok = (int*)(ws + 256 + 65536);
  float* slot_w = (float*)(ws + 256 + 98304);

  hipMemsetAsync(d_ws, 0, 256, stream);  // counts + cursor
  hipMemsetAsync(d_out, 0, (size_t)T_TOK * H_DIM * sizeof(float), stream);

  k_router<<<T_TOK, 64, 0, stream>>>(x, gate_w, tokE, tokP, counts);
  k_offsets<<<1, 64, 0, stream>>>(counts, offsets);
  k_scatter<<<T_TOK / 256, 256, 0, stream>>>(tokE, tokP, offsets, cursor, slot_tok, slot_w);

  // fast-path workspace layout
  const size_t OFF_XB  = 262144;                       // 8 MiB bf16 x
  const size_t OFF_HID = OFF_XB + 8388608;             // 64 MiB bf16 hidden
  const size_t OFF_WG  = OFF_HID + 67108864;           // 64 MiB bf16 wg
  const size_t OFF_WU  = OFF_WG + 67108864;            // 64 MiB bf16 wu
  const size_t NEED    = OFF_WU + 67108864;            // wd aliases OFF_WG

  if (ws_size >= NEED) {
    unsigned short* xb  = (unsigned short*)(ws + OFF_XB);
    unsigned short* hid = (unsigned short*)(ws + OFF_HID);
    unsigned short* wgb = (unsigned short*)(ws + OFF_WG);
    unsigned short* wub = (unsigned short*)(ws + OFF_WU);
    unsigned short* wdb = wgb;  // aliased: stream-serialized after k_gateup3

    k_cvt<<<2048, 256, 0, stream>>>(x, xb, T_TOK * H_DIM / 4);
    k_cvt<<<2048, 256, 0, stream>>>(wg, wgb, E_NUM * I_DIM * H_DIM / 4);
    k_cvt<<<2048, 256, 0, stream>>>(wu, wub, E_NUM * I_DIM * H_DIM / 4);
    k_gateup3<<<dim3(I_DIM / 128, 32, E_NUM), 256, 0, stream>>>(
        xb, wgb, wub, counts, offsets, slot_tok, hid);
    k_cvt<<<2048, 256, 0, stream>>>(wd, wdb, E_NUM * H_DIM * I_DIM / 4);
    k_down3<<<dim3(H_DIM / 128, 32, E_NUM), 256, 0, stream>>>(
        hid, wdb, counts, offsets, slot_tok, slot_w, out);
  } else {
    unsigned short* hid = (unsigned short*)(ws + 131328);
    k_gateup_v1<<<dim3(I_DIM / 128, 32, E_NUM), 256, 0, stream>>>(
        x, wg, wu, counts, offsets, slot_tok, hid);
    k_down_v1<<<dim3(H_DIM / 128, 32, E_NUM), 256, 0, stream>>>(
        hid, wd, counts, offsets, slot_tok, slot_w, out);
  }
}

// Round 6
// 599.316 us; speedup vs baseline: 1.1602x; 1.0683x over previous
//
#include <hip/hip_runtime.h>
#include <math.h>

#define T_TOK 4096
#define H_DIM 1024
#define E_NUM 8
#define I_DIM 4096

typedef __attribute__((ext_vector_type(4))) float f32x4;
typedef __attribute__((ext_vector_type(8))) short bf16x8;

__device__ inline unsigned short f2bf(float f) {
  unsigned int u = __float_as_uint(f);
  u += 0x7fffu + ((u >> 16) & 1u);   // RNE (finite data only)
  return (unsigned short)(u >> 16);
}

__device__ inline void cvt_store4(unsigned short* dst, const float* src) {
  f32x4 v = *reinterpret_cast<const f32x4*>(src);
  ushort4 o;
  o.x = f2bf(v[0]); o.y = f2bf(v[1]); o.z = f2bf(v[2]); o.w = f2bf(v[3]);
  *reinterpret_cast<ushort4*>(dst) = o;
}

// async global->LDS, 16B per lane; LDS dest is wave-uniform base + lane*16
__device__ inline void gll16(const void* g, void* l) {
  __builtin_amdgcn_global_load_lds(
      (const __attribute__((address_space(1))) void*)g,
      (__attribute__((address_space(3))) void*)l, 16, 0, 0);
}

// ---------------- router: fp32 logits, exact top-2 + softmax ----------------
__global__ __launch_bounds__(64) void k_router(const float* __restrict__ x,
                                               const float* __restrict__ gw,
                                               int2* __restrict__ tokE,
                                               float2* __restrict__ tokP,
                                               int* __restrict__ counts) {
  const int t = blockIdx.x;
  const int l = threadIdx.x;
  const float* xr = x + (size_t)t * H_DIM;
  float acc[E_NUM];
#pragma unroll
  for (int e = 0; e < E_NUM; e++) acc[e] = 0.f;
  for (int h = l; h < H_DIM; h += 64) {
    float xv = xr[h];
#pragma unroll
    for (int e = 0; e < E_NUM; e++) acc[e] += xv * gw[e * H_DIM + h];
  }
#pragma unroll
  for (int e = 0; e < E_NUM; e++) {
#pragma unroll
    for (int off = 32; off > 0; off >>= 1) acc[e] += __shfl_xor(acc[e], off);
  }
  if (l == 0) {
    float v0 = -1e30f, v1 = -1e30f;
    int e0 = 0, e1 = 0;
#pragma unroll
    for (int e = 0; e < E_NUM; e++) {
      float v = acc[e];
      if (v > v0) { v1 = v0; e1 = e0; v0 = v; e0 = e; }
      else if (v > v1) { v1 = v; e1 = e; }
    }
    float ex = expf(v1 - v0);
    float p0 = 1.f / (1.f + ex);
    float p1 = ex * p0;
    tokE[t] = make_int2(e0, e1);
    tokP[t] = make_float2(p0, p1);
    atomicAdd(&counts[e0], 1);
    atomicAdd(&counts[e1], 1);
  }
}

__global__ void k_offsets(const int* __restrict__ counts, int* __restrict__ offsets) {
  if (threadIdx.x == 0 && blockIdx.x == 0) {
    int s = 0;
    for (int e = 0; e < E_NUM; e++) { offsets[e] = s; s += counts[e]; }
    offsets[E_NUM] = s;
  }
}

__global__ __launch_bounds__(256) void k_scatter(const int2* __restrict__ tokE,
                                                 const float2* __restrict__ tokP,
                                                 const int* __restrict__ offsets,
                                                 int* __restrict__ cursor,
                                                 int* __restrict__ slot_tok,
                                                 float* __restrict__ slot_w) {
  int t = blockIdx.x * 256 + threadIdx.x;
  if (t >= T_TOK) return;
  int2 e = tokE[t];
  float2 p = tokP[t];
  int pos0 = atomicAdd(&cursor[e.x], 1);
  slot_tok[offsets[e.x] + pos0] = t;
  slot_w[offsets[e.x] + pos0] = p.x;
  int pos1 = atomicAdd(&cursor[e.y], 1);
  slot_tok[offsets[e.y] + pos1] = t;
  slot_w[offsets[e.y] + pos1] = p.y;
}

// ---------------- fp32 -> bf16 bulk convert (memory-bound) ------------------
__global__ __launch_bounds__(256) void k_cvt(const float* __restrict__ src,
                                             unsigned short* __restrict__ dst,
                                             int n4) {
  int i = blockIdx.x * 256 + threadIdx.x;
  const int stride = gridDim.x * 256;
  for (; i < n4; i += stride) {
    f32x4 v = reinterpret_cast<const f32x4*>(src)[i];
    ushort4 o;
    o.x = f2bf(v[0]); o.y = f2bf(v[1]); o.z = f2bf(v[2]); o.w = f2bf(v[3]);
    reinterpret_cast<ushort4*>(dst)[i] = o;
  }
}

// === FAST PATH: 128x128 tiles, BK=32, TRIPLE-buffer LDS, depth-2 prefetch ===
// 256 thr = 4 waves (2x2), wave tile 64x64. Swizzle (bank-exact for 64B rows):
// 16B chunk c of row r stored at chunk c ^ ((r>>1)&3), applied on the global
// SOURCE (staging) and the ds_read address (rule #21) -- verified 0 conflicts.
// Pipeline ledger (per wave, L loads/tile): enter step t with tiles {t,t+1}
// in flight (2L outstanding); issue tile t+2 (3L); s_waitcnt vmcnt(2L) drains
// exactly tile t; barrier; compute buf t%3; barrier. Buf (t+2)%3 was last
// read in step t-1, and the issue is after step t-1's trailing barrier.

// pass 1: hidden = silu(Xe @ wg^T) * (Xe @ wu^T)   [dual-B, L=6]
__global__ __launch_bounds__(256, 2) void k_gateup4(
    const unsigned short* __restrict__ xb, const unsigned short* __restrict__ wgb,
    const unsigned short* __restrict__ wub, const int* __restrict__ counts,
    const int* __restrict__ offsets, const int* __restrict__ slot_tok,
    unsigned short* __restrict__ hidden) {
  const int e = blockIdx.z;
  const int cnt = counts[e];
  const int m0 = blockIdx.y * 128;
  if (m0 >= cnt) return;
  const int n0 = blockIdx.x * 128;
  const int base = offsets[e];

  __shared__ unsigned short As[3][128 * 32];   // 24 KiB
  __shared__ unsigned short Bg[3][128 * 32];   // 24 KiB
  __shared__ unsigned short Bu[3][128 * 32];   // 24 KiB

  const int tid = threadIdx.x;
  const int wave = tid >> 6;
  const int lane = tid & 63;
  const int wm = (wave >> 1) * 64;
  const int wn = (wave & 1) * 64;
  const int lr = lane & 15;
  const int lk = lane >> 4;

  const int sr = lane >> 2;            // 0..15
  const int sc = lane & 3;             // 0..3
  const int swz = ((sc ^ ((sr >> 1) & 3)) << 3);  // bank-exact source swizzle

  const size_t wboff = (size_t)e * (size_t)I_DIM * H_DIM;
  const unsigned short* srcA[2];
  const unsigned short* srcBg[2];
  const unsigned short* srcBu[2];
  const int dstoff[2] = {(wave * 32) * 32, (wave * 32 + 16) * 32};
#pragma unroll
  for (int i = 0; i < 2; i++) {
    int row = wave * 32 + i * 16 + sr;
    int gr = m0 + row; if (gr > cnt - 1) gr = cnt - 1;
    srcA[i]  = xb + (size_t)slot_tok[base + gr] * H_DIM + swz;
    srcBg[i] = wgb + wboff + (size_t)(n0 + row) * H_DIM + swz;
    srcBu[i] = wub + wboff + (size_t)(n0 + row) * H_DIM + swz;
  }

  f32x4 accg[4][4], accu[4][4];
#pragma unroll
  for (int i = 0; i < 4; i++)
#pragma unroll
    for (int j = 0; j < 4; j++) {
      accg[i][j] = (f32x4){0.f, 0.f, 0.f, 0.f};
      accu[i][j] = (f32x4){0.f, 0.f, 0.f, 0.f};
    }

  const int koff = ((lk ^ ((lr >> 1) & 3)) << 3);   // read-side, same involution

  // drain init loads so the vmcnt ledger is exact
  asm volatile("s_waitcnt vmcnt(0)" ::: "memory");

  // prologue: tiles 0 and 1 into bufs 0 and 1 (12 outstanding)
#pragma unroll
  for (int i = 0; i < 2; i++) {
    gll16(srcBg[i], &Bg[0][dstoff[i]]);
    gll16(srcBu[i], &Bu[0][dstoff[i]]);
    gll16(srcA[i],  &As[0][dstoff[i]]);
  }
#pragma unroll
  for (int i = 0; i < 2; i++) {
    gll16(srcBg[i] + 32, &Bg[1][dstoff[i]]);
    gll16(srcBu[i] + 32, &Bu[1][dstoff[i]]);
    gll16(srcA[i] + 32,  &As[1][dstoff[i]]);
  }

  const int NT = H_DIM / 32;   // 32
  int bb = 0;
  for (int t = 0; t < NT; t++) {
    int nb = bb + 2; if (nb >= 3) nb -= 3;
    const int kn = (t + 2 < NT) ? (t + 2) * 32 : 0;  // wrap: dummy in-bounds
    // issue tile t+2 (6) -> 18 outstanding; wait to 12 = tile t landed
    gll16(srcBg[0] + kn, &Bg[nb][dstoff[0]]);
    gll16(srcBg[1] + kn, &Bg[nb][dstoff[1]]);
    gll16(srcBu[0] + kn, &Bu[nb][dstoff[0]]);
    gll16(srcBu[1] + kn, &Bu[nb][dstoff[1]]);
    gll16(srcA[0] + kn,  &As[nb][dstoff[0]]);
    gll16(srcA[1] + kn,  &As[nb][dstoff[1]]);
    asm volatile("s_waitcnt vmcnt(12)" ::: "memory");
    __builtin_amdgcn_s_barrier();

    bf16x8 af[4];
#pragma unroll
    for (int mf = 0; mf < 4; mf++)
      af[mf] = *reinterpret_cast<const bf16x8*>(&As[bb][(wm + mf * 16 + lr) * 32 + koff]);
    __builtin_amdgcn_s_setprio(1);
#pragma unroll
    for (int nf = 0; nf < 4; nf++) {
      const int ro = (wn + nf * 16 + lr) * 32 + koff;
      bf16x8 bg = *reinterpret_cast<const bf16x8*>(&Bg[bb][ro]);
      bf16x8 bu = *reinterpret_cast<const bf16x8*>(&Bu[bb][ro]);
#pragma unroll
      for (int mf = 0; mf < 4; mf++) {
        accg[mf][nf] = __builtin_amdgcn_mfma_f32_16x16x32_bf16(af[mf], bg, accg[mf][nf], 0, 0, 0);
        accu[mf][nf] = __builtin_amdgcn_mfma_f32_16x16x32_bf16(af[mf], bu, accu[mf][nf], 0, 0, 0);
      }
    }
    __builtin_amdgcn_s_setprio(0);
    __builtin_amdgcn_s_barrier();
    bb++; if (bb == 3) bb = 0;
  }
  asm volatile("s_waitcnt vmcnt(0)" ::: "memory");  // drain dummy prefetches

  // epilogue: h = silu(g) * u, store bf16
#pragma unroll
  for (int mf = 0; mf < 4; mf++) {
#pragma unroll
    for (int j = 0; j < 4; j++) {
      int row = wm + mf * 16 + lk * 4 + j;
      if (m0 + row < cnt) {
        size_t hbase = (size_t)(base + m0 + row) * I_DIM;
#pragma unroll
        for (int nf = 0; nf < 4; nf++) {
          int col = n0 + wn + nf * 16 + lr;
          float g = accg[mf][nf][j];
          float u = accu[mf][nf][j];
          hidden[hbase + col] = f2bf(g / (1.f + expf(-g)) * u);
        }
      }
    }
  }
}

// pass 2: out[t] += w * (hidden_row @ wd^T)   [single-B, K=I=4096, L=4]
__global__ __launch_bounds__(256, 2) void k_down4(
    const unsigned short* __restrict__ hidden, const unsigned short* __restrict__ wdb,
    const int* __restrict__ counts, const int* __restrict__ offsets,
    const int* __restrict__ slot_tok, const float* __restrict__ slot_w,
    float* __restrict__ out) {
  const int e = blockIdx.z;
  const int cnt = counts[e];
  const int m0 = blockIdx.y * 128;
  if (m0 >= cnt) return;
  const int n0 = blockIdx.x * 128;
  const int base = offsets[e];

  __shared__ unsigned short As[3][128 * 32];   // 24 KiB
  __shared__ unsigned short Bs[3][128 * 32];   // 24 KiB

  const int tid = threadIdx.x;
  const int wave = tid >> 6;
  const int lane = tid & 63;
  const int wm = (wave >> 1) * 64;
  const int wn = (wave & 1) * 64;
  const int lr = lane & 15;
  const int lk = lane >> 4;

  const int sr = lane >> 2;
  const int sc = lane & 3;
  const int swz = ((sc ^ ((sr >> 1) & 3)) << 3);

  const unsigned short* srcA[2];
  const unsigned short* srcB[2];
  const int dstoff[2] = {(wave * 32) * 32, (wave * 32 + 16) * 32};
#pragma unroll
  for (int i = 0; i < 2; i++) {
    int row = wave * 32 + i * 16 + sr;
    int gr = m0 + row; if (gr > cnt - 1) gr = cnt - 1;
    srcA[i] = hidden + (size_t)(base + gr) * I_DIM + swz;
    srcB[i] = wdb + (size_t)e * H_DIM * I_DIM + (size_t)(n0 + row) * I_DIM + swz;
  }

  f32x4 acc[4][4];
#pragma unroll
  for (int i = 0; i < 4; i++)
#pragma unroll
    for (int j = 0; j < 4; j++) acc[i][j] = (f32x4){0.f, 0.f, 0.f, 0.f};

  const int koff = ((lk ^ ((lr >> 1) & 3)) << 3);

  asm volatile("s_waitcnt vmcnt(0)" ::: "memory");

  // prologue: tiles 0 and 1 (8 outstanding)
#pragma unroll
  for (int i = 0; i < 2; i++) {
    gll16(srcB[i], &Bs[0][dstoff[i]]);
    gll16(srcA[i], &As[0][dstoff[i]]);
  }
#pragma unroll
  for (int i = 0; i < 2; i++) {
    gll16(srcB[i] + 32, &Bs[1][dstoff[i]]);
    gll16(srcA[i] + 32, &As[1][dstoff[i]]);
  }

  const int NT = I_DIM / 32;   // 128
  int bb = 0;
  for (int t = 0; t < NT; t++) {
    int nb = bb + 2; if (nb >= 3) nb -= 3;
    const int kn = (t + 2 < NT) ? (t + 2) * 32 : 0;
    gll16(srcB[0] + kn, &Bs[nb][dstoff[0]]);
    gll16(srcB[1] + kn, &Bs[nb][dstoff[1]]);
    gll16(srcA[0] + kn, &As[nb][dstoff[0]]);
    gll16(srcA[1] + kn, &As[nb][dstoff[1]]);
    asm volatile("s_waitcnt vmcnt(8)" ::: "memory");
    __builtin_amdgcn_s_barrier();

    bf16x8 af[4];
#pragma unroll
    for (int mf = 0; mf < 4; mf++)
      af[mf] = *reinterpret_cast<const bf16x8*>(&As[bb][(wm + mf * 16 + lr) * 32 + koff]);
    __builtin_amdgcn_s_setprio(1);
#pragma unroll
    for (int nf = 0; nf < 4; nf++) {
      bf16x8 bf = *reinterpret_cast<const bf16x8*>(&Bs[bb][(wn + nf * 16 + lr) * 32 + koff]);
#pragma unroll
      for (int mf = 0; mf < 4; mf++)
        acc[mf][nf] = __builtin_amdgcn_mfma_f32_16x16x32_bf16(af[mf], bf, acc[mf][nf], 0, 0, 0);
    }
    __builtin_amdgcn_s_setprio(0);
    __builtin_amdgcn_s_barrier();
    bb++; if (bb == 3) bb = 0;
  }
  asm volatile("s_waitcnt vmcnt(0)" ::: "memory");

#pragma unroll
  for (int mf = 0; mf < 4; mf++) {
#pragma unroll
    for (int j = 0; j < 4; j++) {
      int row = wm + mf * 16 + lk * 4 + j;
      if (m0 + row < cnt) {
        int slot = base + m0 + row;
        int t = slot_tok[slot];
        float w = slot_w[slot];
#pragma unroll
        for (int nf = 0; nf < 4; nf++) {
          int col = n0 + wn + nf * 16 + lr;
          atomicAdd(&out[(size_t)t * H_DIM + col], w * acc[mf][nf][j]);
        }
      }
    }
  }
}

// ================= FALLBACK PATH (fp32 in-loop convert, proven) =============
__global__ __launch_bounds__(256) void k_gateup_v1(
    const float* __restrict__ x, const float* __restrict__ wg,
    const float* __restrict__ wu, const int* __restrict__ counts,
    const int* __restrict__ offsets, const int* __restrict__ slot_tok,
    unsigned short* __restrict__ hidden) {
  const int e = blockIdx.z;
  const int cnt = counts[e];
  const int m0 = blockIdx.y * 128;
  if (m0 >= cnt) return;
  const int n0 = blockIdx.x * 128;
  const int base = offsets[e];

  __shared__ unsigned short As[128 * 40];
  __shared__ unsigned short Bgs[128 * 40];
  __shared__ unsigned short Bus[128 * 40];

  const int tid = threadIdx.x;
  const int wave = tid >> 6;
  const int lane = tid & 63;
  const int wm = (wave >> 1) * 64;
  const int wn = (wave & 1) * 64;
  const int lr = lane & 15;
  const int lk = lane >> 4;
  const int r_sub = tid >> 3;
  const int kq = (tid & 7) * 4;

  const float* wge = wg + (size_t)e * I_DIM * H_DIM;
  const float* wue = wu + (size_t)e * I_DIM * H_DIM;

  const float* aptr[4];
  const float* bgptr[4];
  const float* buptr[4];
#pragma unroll
  for (int p = 0; p < 4; p++) {
    int row = p * 32 + r_sub;
    int gr = m0 + row;
    if (gr > cnt - 1) gr = cnt - 1;
    aptr[p] = x + (size_t)slot_tok[base + gr] * H_DIM + kq;
    bgptr[p] = wge + (size_t)(n0 + row) * H_DIM + kq;
    buptr[p] = wue + (size_t)(n0 + row) * H_DIM + kq;
  }

  f32x4 accg[4][4], accu[4][4];
#pragma unroll
  for (int i = 0; i < 4; i++)
#pragma unroll
    for (int j = 0; j < 4; j++) {
      accg[i][j] = (f32x4){0.f, 0.f, 0.f, 0.f};
      accu[i][j] = (f32x4){0.f, 0.f, 0.f, 0.f};
    }

  for (int k0 = 0; k0 < H_DIM; k0 += 32) {
#pragma unroll
    for (int p = 0; p < 4; p++) {
      int row = p * 32 + r_sub;
      cvt_store4(&As[row * 40 + kq], aptr[p] + k0);
      cvt_store4(&Bgs[row * 40 + kq], bgptr[p] + k0);
      cvt_store4(&Bus[row * 40 + kq], buptr[p] + k0);
    }
    __syncthreads();
    bf16x8 af[4];
#pragma unroll
    for (int mf = 0; mf < 4; mf++)
      af[mf] = *reinterpret_cast<const bf16x8*>(&As[(wm + mf * 16 + lr) * 40 + lk * 8]);
#pragma unroll
    for (int nf = 0; nf < 4; nf++) {
      bf16x8 bg = *reinterpret_cast<const bf16x8*>(&Bgs[(wn + nf * 16 + lr) * 40 + lk * 8]);
      bf16x8 bu = *reinterpret_cast<const bf16x8*>(&Bus[(wn + nf * 16 + lr) * 40 + lk * 8]);
#pragma unroll
      for (int mf = 0; mf < 4; mf++) {
        accg[mf][nf] = __builtin_amdgcn_mfma_f32_16x16x32_bf16(af[mf], bg, accg[mf][nf], 0, 0, 0);
        accu[mf][nf] = __builtin_amdgcn_mfma_f32_16x16x32_bf16(af[mf], bu, accu[mf][nf], 0, 0, 0);
      }
    }
    __syncthreads();
  }

#pragma unroll
  for (int mf = 0; mf < 4; mf++) {
#pragma unroll
    for (int j = 0; j < 4; j++) {
      int row = wm + mf * 16 + lk * 4 + j;
      if (m0 + row < cnt) {
        size_t hbase = (size_t)(base + m0 + row) * I_DIM;
#pragma unroll
        for (int nf = 0; nf < 4; nf++) {
          int col = n0 + wn + nf * 16 + lr;
          float g = accg[mf][nf][j];
          float u = accu[mf][nf][j];
          float h = g / (1.f + expf(-g)) * u;
          hidden[hbase + col] = f2bf(h);
        }
      }
    }
  }
}

__global__ __launch_bounds__(256) void k_down_v1(
    const unsigned short* __restrict__ hidden, const float* __restrict__ wd,
    const int* __restrict__ counts, const int* __restrict__ offsets,
    const int* __restrict__ slot_tok, const float* __restrict__ slot_w,
    float* __restrict__ out) {
  const int e = blockIdx.z;
  const int cnt = counts[e];
  const int m0 = blockIdx.y * 128;
  if (m0 >= cnt) return;
  const int n0 = blockIdx.x * 128;
  const int base = offsets[e];

  __shared__ unsigned short As[128 * 40];
  __shared__ unsigned short Bs[128 * 40];

  const int tid = threadIdx.x;
  const int wave = tid >> 6;
  const int lane = tid & 63;
  const int wm = (wave >> 1) * 64;
  const int wn = (wave & 1) * 64;
  const int lr = lane & 15;
  const int lk = lane >> 4;
  const int r_sub = tid >> 3;
  const int kq = (tid & 7) * 4;

  const unsigned short* ap[4];
  const float* bp[4];
#pragma unroll
  for (int p = 0; p < 4; p++) {
    int row = p * 32 + r_sub;
    int gr = m0 + row;
    if (gr > cnt - 1) gr = cnt - 1;
    ap[p] = hidden + (size_t)(base + gr) * I_DIM + kq;
    bp[p] = wd + (size_t)e * H_DIM * I_DIM + (size_t)(n0 + row) * I_DIM + kq;
  }

  f32x4 acc[4][4];
#pragma unroll
  for (int i = 0; i < 4; i++)
#pragma unroll
    for (int j = 0; j < 4; j++) acc[i][j] = (f32x4){0.f, 0.f, 0.f, 0.f};

  for (int k0 = 0; k0 < I_DIM; k0 += 32) {
#pragma unroll
    for (int p = 0; p < 4; p++) {
      int row = p * 32 + r_sub;
      *reinterpret_cast<ushort4*>(&As[row * 40 + kq]) =
          *reinterpret_cast<const ushort4*>(ap[p] + k0);
      cvt_store4(&Bs[row * 40 + kq], bp[p] + k0);
    }
    __syncthreads();
    bf16x8 af[4];
#pragma unroll
    for (int mf = 0; mf < 4; mf++)
      af[mf] = *reinterpret_cast<const bf16x8*>(&As[(wm + mf * 16 + lr) * 40 + lk * 8]);
#pragma unroll
    for (int nf = 0; nf < 4; nf++) {
      bf16x8 bf = *reinterpret_cast<const bf16x8*>(&Bs[(wn + nf * 16 + lr) * 40 + lk * 8]);
#pragma unroll
      for (int mf = 0; mf < 4; mf++)
        acc[mf][nf] = __builtin_amdgcn_mfma_f32_16x16x32_bf16(af[mf], bf, acc[mf][nf], 0, 0, 0);
    }
    __syncthreads();
  }

#pragma unroll
  for (int mf = 0; mf < 4; mf++) {
#pragma unroll
    for (int j = 0; j < 4; j++) {
      int row = wm + mf * 16 + lk * 4 + j;
      if (m0 + row < cnt) {
        int slot = base + m0 + row;
        int t = slot_tok[slot];
        float w = slot_w[slot];
#pragma unroll
        for (int nf = 0; nf < 4; nf++) {
          int col = n0 + wn + nf * 16 + lr;
          atomicAdd(&out[(size_t)t * H_DIM + col], w * acc[mf][nf][j]);
        }
      }
    }
  }
}

extern "C" void kernel_launch(void* const* d_in, const int* in_sizes, int n_in,
                              void* d_out, int out_size, void* d_ws, size_t ws_size,
                              hipStream_t stream) {
  const float* x = (const float*)d_in[0];
  const float* gate_w = (const float*)d_in[1];
  const float* wg = (const float*)d_in[2];
  const float* wu = (const float*)d_in[3];
  const float* wd = (const float*)d_in[4];
  float* out = (float*)d_out;

  char* ws = (char*)d_ws;
  int* counts = (int*)(ws + 0);
  int* cursor = (int*)(ws + 64);
  int* offsets = (int*)(ws + 128);
  int2* tokE = (int2*)(ws + 256);
  float2* tokP = (float2*)(ws + 256 + 32768);
  int* slot_tok = (int*)(ws + 256 + 65536);
  float* slot_w = (float*)(ws + 256 + 98304);

  hipMemsetAsync(d_ws, 0, 256, stream);  // counts + cursor
  hipMemsetAsync(d_out, 0, (size_t)T_TOK * H_DIM * sizeof(float), stream);

  k_router<<<T_TOK, 64, 0, stream>>>(x, gate_w, tokE, tokP, counts);
  k_offsets<<<1, 64, 0, stream>>>(counts, offsets);
  k_scatter<<<T_TOK / 256, 256, 0, stream>>>(tokE, tokP, offsets, cursor, slot_tok, slot_w);

  // fast-path workspace layout
  const size_t OFF_XB  = 262144;                       // 8 MiB bf16 x
  const size_t OFF_HID = OFF_XB + 8388608;             // 64 MiB bf16 hidden
  const size_t OFF_WG  = OFF_HID + 67108864;           // 64 MiB bf16 wg
  const size_t OFF_WU  = OFF_WG + 67108864;            // 64 MiB bf16 wu
  const size_t NEED    = OFF_WU + 67108864;            // wd aliases OFF_WG

  if (ws_size >= NEED) {
    unsigned short* xb  = (unsigned short*)(ws + OFF_XB);
    unsigned short* hid = (unsigned short*)(ws + OFF_HID);
    unsigned short* wgb = (unsigned short*)(ws + OFF_WG);
    unsigned short* wub = (unsigned short*)(ws + OFF_WU);
    unsigned short* wdb = wgb;  // aliased: stream-serialized after k_gateup4

    k_cvt<<<2048, 256, 0, stream>>>(x, xb, T_TOK * H_DIM / 4);
    k_cvt<<<2048, 256, 0, stream>>>(wg, wgb, E_NUM * I_DIM * H_DIM / 4);
    k_cvt<<<2048, 256, 0, stream>>>(wu, wub, E_NUM * I_DIM * H_DIM / 4);
    k_gateup4<<<dim3(I_DIM / 128, 32, E_NUM), 256, 0, stream>>>(
        xb, wgb, wub, counts, offsets, slot_tok, hid);
    k_cvt<<<2048, 256, 0, stream>>>(wd, wdb, E_NUM * H_DIM * I_DIM / 4);
    k_down4<<<dim3(H_DIM / 128, 32, E_NUM), 256, 0, stream>>>(
        hid, wdb, counts, offsets, slot_tok, slot_w, out);
  } else {
    unsigned short* hid = (unsigned short*)(ws + 131328);
    k_gateup_v1<<<dim3(I_DIM / 128, 32, E_NUM), 256, 0, stream>>>(
        x, wg, wu, counts, offsets, slot_tok, hid);
    k_down_v1<<<dim3(H_DIM / 128, 32, E_NUM), 256, 0, stream>>>(
        hid, wd, counts, offsets, slot_tok, slot_w, out);
  }
}